// Round 1
// baseline (695.505 us; speedup 1.0000x reference)
//
#include <hip/hip_runtime.h>

typedef __attribute__((ext_vector_type(8))) short bh8;   // 8 bf16 in 4 VGPRs
typedef __attribute__((ext_vector_type(4))) float f4;    // MFMA accumulator

typedef unsigned short u16;
typedef unsigned int u32;

__device__ inline u16 f2b(float f) {
  union { float f; u32 u; } v; v.f = f;
  u32 u = v.u;
  u32 r = (u + 0x7FFFu + ((u >> 16) & 1u)) >> 16;  // round-to-nearest-even
  return (u16)r;
}
__device__ inline float b2f(u16 b) {
  union { u32 u; float f; } v; v.u = ((u32)b) << 16;
  return v.f;
}

// ---------------- prep: cast x to bf16 ----------------
__global__ __launch_bounds__(256) void k_cvt_x(const float* __restrict__ x,
                                               u16* __restrict__ xb) {
  int i = (blockIdx.x * 256 + threadIdx.x) * 4;
  float4 v = *(const float4*)&x[i];
  ushort4 o;
  o.x = f2b(v.x); o.y = f2b(v.y); o.z = f2b(v.z); o.w = f2b(v.w);
  *(ushort4*)&xb[i] = o;
}

// ---------------- prep: transpose weight (K x N f32) -> (N x K bf16) ----------------
__global__ __launch_bounds__(256) void k_transpose(const float* __restrict__ W,
                                                   u16* __restrict__ WT,
                                                   int K, int N) {
  __shared__ u16 t[32][33];
  int bx = blockIdx.x * 32, by = blockIdx.y * 32;
  int x = threadIdx.x & 31, y = threadIdx.x >> 5;  // y in 0..7
  for (int j = 0; j < 4; ++j) {
    int r = y + j * 8;
    t[r][x] = f2b(W[(size_t)(by + r) * N + bx + x]);
  }
  __syncthreads();
  for (int j = 0; j < 4; ++j) {
    int r = y + j * 8;
    WT[(size_t)(bx + r) * K + by + x] = t[x][r];  // WT[n][k] = W[k][n]
  }
}

// ---------------- GEMM: C[M,N] = A[M,K](bf16) * Bt[N,K](bf16, pre-transposed B) ----------------
// 128x128 tile, BK=64, 4 waves (2x2), each wave 64x64 via 4x4 MFMA 16x16x32 frags.
__global__ __launch_bounds__(256) void k_gemm(const u16* __restrict__ A,
                                              const u16* __restrict__ Bt,
                                              u16* __restrict__ Cb,
                                              float* __restrict__ Cf,
                                              int M, int N, int K) {
  __shared__ u16 As[128][72];   // pad row to 72 elems (144B) -> 16B-aligned chunks
  __shared__ u16 Bs[128][72];
  const int tid = threadIdx.x;
  const int lane = tid & 63, wid = tid >> 6;
  const int l15 = lane & 15, lg = lane >> 4;
  const int bm = blockIdx.x * 128, bn = blockIdx.y * 128;
  const int wr = (wid >> 1) * 64, wc = (wid & 1) * 64;
  f4 acc[4][4] = {};

  for (int kb = 0; kb < K; kb += 64) {
    __syncthreads();  // previous iter's frag reads done before overwrite
    for (int c = 0; c < 4; ++c) {
      int i = c * 256 + tid;
      int r = i >> 3, cc = (i & 7) * 8;
      *(uint4*)&As[r][cc] = *(const uint4*)&A[(size_t)(bm + r) * K + kb + cc];
      *(uint4*)&Bs[r][cc] = *(const uint4*)&Bt[(size_t)(bn + r) * K + kb + cc];
    }
    __syncthreads();
    for (int kk = 0; kk < 2; ++kk) {
      bh8 a[4], b[4];
      for (int m = 0; m < 4; ++m)
        a[m] = *(const bh8*)&As[wr + m * 16 + l15][kk * 32 + lg * 8];
      for (int n = 0; n < 4; ++n)
        b[n] = *(const bh8*)&Bs[wc + n * 16 + l15][kk * 32 + lg * 8];
      for (int m = 0; m < 4; ++m)
        for (int n = 0; n < 4; ++n)
          acc[m][n] = __builtin_amdgcn_mfma_f32_16x16x32_bf16(a[m], b[n], acc[m][n], 0, 0, 0);
    }
  }
  // D layout: col = lane&15, row = (lane>>4)*4 + reg   [m89-verified]
  for (int m = 0; m < 4; ++m)
    for (int n = 0; n < 4; ++n)
      for (int r = 0; r < 4; ++r) {
        int row = bm + wr + m * 16 + lg * 4 + r;
        int col = bn + wc + n * 16 + l15;
        float v = acc[m][n][r];
        if (Cf) Cf[(size_t)row * N + col] = v;
        else    Cb[(size_t)row * N + col] = f2b(v);
      }
}

// ---------------- RMSNorm + RoPE; scatter qkv -> Q/K/V [B,H,L,D] bf16 ----------------
__global__ __launch_bounds__(256) void k_normrope(const u16* __restrict__ qkv,
                                                  const float* __restrict__ qw,
                                                  const float* __restrict__ kw,
                                                  const float* __restrict__ cosp,
                                                  const float* __restrict__ sinp,
                                                  u16* __restrict__ Q,
                                                  u16* __restrict__ K,
                                                  u16* __restrict__ V) {
  int gw = blockIdx.x * 4 + (threadIdx.x >> 6);   // one wave per (b,l,h)
  int lane = threadIdx.x & 63;
  int h = gw & 15;
  int bl = gw >> 4;             // b*2048 + l
  int l = bl & 2047;
  int b = bl >> 11;
  const u16* base = qkv + (size_t)bl * 3072 + h * 64;
  float qv = b2f(base[lane]);
  float kv = b2f(base[1024 + lane]);
  float vv = b2f(base[2048 + lane]);
  float qs = qv * qv, ks = kv * kv;
  for (int off = 1; off < 64; off <<= 1) {
    qs += __shfl_xor(qs, off, 64);
    ks += __shfl_xor(ks, off, 64);
  }
  float qr = rsqrtf(qs * (1.0f / 64.0f) + 1e-6f);
  float kr = rsqrtf(ks * (1.0f / 64.0f) + 1e-6f);
  float qn = qv * qr * qw[lane];
  float kn = kv * kr * kw[lane];
  int d2 = lane & 31;
  float c = cosp[l * 32 + d2], s = sinp[l * 32 + d2];
  float qp = __shfl_xor(qn, 32, 64);
  float kp = __shfl_xor(kn, 32, 64);
  float qo = (lane < 32) ? (qn * c - qp * s) : (qp * s + qn * c);
  float ko = (lane < 32) ? (kn * c - kp * s) : (kp * s + kn * c);
  size_t oi = (size_t)((b * 16 + h) * 2048 + l) * 64 + lane;
  Q[oi] = f2b(qo);
  K[oi] = f2b(ko);
  V[oi] = f2b(vv);
}

// ---------------- flash attention, causal; writes attn_out [B*L, HID] bf16 ----------------
// grid: (L/64, B*H); 4 waves, wave handles 16 q rows; key tiles of 32.
__global__ __launch_bounds__(256) void k_attn(const u16* __restrict__ Q,
                                              const u16* __restrict__ K,
                                              const u16* __restrict__ V,
                                              u16* __restrict__ O) {
  int bh = blockIdx.y;
  int b = bh >> 4, h = bh & 15;
  int wid = threadIdx.x >> 6, lane = threadIdx.x & 63;
  int l15 = lane & 15, lg = lane >> 4;
  int qb = blockIdx.x * 64 + wid * 16;
  const u16* Qp = Q + (size_t)bh * 2048 * 64;
  const u16* Kp = K + (size_t)bh * 2048 * 64;
  const u16* Vp = V + (size_t)bh * 2048 * 64;
  __shared__ u16 P_lds[4][16][40];   // per-wave P tile [16 q][32 k], padded row 80B

  bh8 aq0 = *(const bh8*)&Qp[(size_t)(qb + l15) * 64 + lg * 8];
  bh8 aq1 = *(const bh8*)&Qp[(size_t)(qb + l15) * 64 + 32 + lg * 8];

  f4 acc[4] = {};          // out[16 q][64 d]: 4 d-tiles
  float mrow[4], lrow[4];
  for (int r = 0; r < 4; ++r) { mrow[r] = -1e30f; lrow[r] = 0.0f; }

  int nkt = (qb + 47) >> 5;      // covers keys 0..qb+15
  for (int kt = 0; kt < nkt; ++kt) {
    int kb = kt * 32;
    f4 s0 = {}, s1 = {};
    bh8 bk;
    bk = *(const bh8*)&Kp[(size_t)(kb + l15) * 64 + lg * 8];
    s0 = __builtin_amdgcn_mfma_f32_16x16x32_bf16(aq0, bk, s0, 0, 0, 0);
    bk = *(const bh8*)&Kp[(size_t)(kb + l15) * 64 + 32 + lg * 8];
    s0 = __builtin_amdgcn_mfma_f32_16x16x32_bf16(aq1, bk, s0, 0, 0, 0);
    bk = *(const bh8*)&Kp[(size_t)(kb + 16 + l15) * 64 + lg * 8];
    s1 = __builtin_amdgcn_mfma_f32_16x16x32_bf16(aq0, bk, s1, 0, 0, 0);
    bk = *(const bh8*)&Kp[(size_t)(kb + 16 + l15) * 64 + 32 + lg * 8];
    s1 = __builtin_amdgcn_mfma_f32_16x16x32_bf16(aq1, bk, s1, 0, 0, 0);

    float p0[4], p1[4], pm[4];
    for (int r = 0; r < 4; ++r) {
      int q = qb + lg * 4 + r;
      float v0 = s0[r] * 0.125f; if (kb + l15 > q)      v0 = -1e30f;
      float v1 = s1[r] * 0.125f; if (kb + 16 + l15 > q) v1 = -1e30f;
      p0[r] = v0; p1[r] = v1;
      pm[r] = fmaxf(v0, v1);
    }
    for (int off = 1; off < 16; off <<= 1)
      for (int r = 0; r < 4; ++r) pm[r] = fmaxf(pm[r], __shfl_xor(pm[r], off, 64));
    float fac[4], ps[4];
    for (int r = 0; r < 4; ++r) {
      float mnew = fmaxf(mrow[r], pm[r]);
      fac[r] = __expf(mrow[r] - mnew);
      mrow[r] = mnew;
      p0[r] = __expf(p0[r] - mnew);
      p1[r] = __expf(p1[r] - mnew);
      ps[r] = p0[r] + p1[r];
    }
    for (int off = 1; off < 16; off <<= 1)
      for (int r = 0; r < 4; ++r) ps[r] += __shfl_xor(ps[r], off, 64);
    for (int r = 0; r < 4; ++r) lrow[r] = lrow[r] * fac[r] + ps[r];
    for (int n = 0; n < 4; ++n)
      for (int r = 0; r < 4; ++r) acc[n][r] *= fac[r];

    // P (16x32) -> LDS in A-frag order
    for (int r = 0; r < 4; ++r) {
      P_lds[wid][lg * 4 + r][l15]      = f2b(p0[r]);
      P_lds[wid][lg * 4 + r][16 + l15] = f2b(p1[r]);
    }
    asm volatile("s_waitcnt lgkmcnt(0)" ::: "memory");
    bh8 pa = *(const bh8*)&P_lds[wid][l15][lg * 8];

    for (int n = 0; n < 4; ++n) {
      bh8 bv;
      for (int j = 0; j < 8; ++j)
        bv[j] = (short)Vp[(size_t)(kb + lg * 8 + j) * 64 + n * 16 + l15];
      acc[n] = __builtin_amdgcn_mfma_f32_16x16x32_bf16(pa, bv, acc[n], 0, 0, 0);
    }
  }

  for (int n = 0; n < 4; ++n)
    for (int r = 0; r < 4; ++r) {
      int q = qb + lg * 4 + r;
      int d = n * 16 + l15;
      float o = acc[n][r] / lrow[r];
      O[((size_t)b * 2048 + q) * 1024 + h * 64 + d] = f2b(o);
    }
}

extern "C" void kernel_launch(void* const* d_in, const int* in_sizes, int n_in,
                              void* d_out, int out_size, void* d_ws, size_t ws_size,
                              hipStream_t stream) {
  (void)in_sizes; (void)n_in; (void)out_size; (void)ws_size;
  const float* x    = (const float*)d_in[0];
  const float* Wqkv = (const float*)d_in[1];
  const float* Wo   = (const float*)d_in[2];
  const float* qw   = (const float*)d_in[3];
  const float* kw   = (const float*)d_in[4];
  const float* cosp = (const float*)d_in[5];
  const float* sinp = (const float*)d_in[6];
  float* out = (float*)d_out;

  char* ws = (char*)d_ws;
  u16* xb    = (u16*)(ws);                 //  8,388,608 B  x bf16 [4096][1024]
  u16* wqkvT = (u16*)(ws + 8388608);       //  6,291,456 B  Wqkv^T bf16 [3072][1024]
  u16* woT   = (u16*)(ws + 14680064);      //  2,097,152 B  Wo^T bf16 [1024][1024]
  u16* qkv   = (u16*)(ws + 16777216);      // 25,165,824 B  qkv bf16 [4096][3072]
  u16* Qb    = (u16*)(ws + 41943040);      //  8,388,608 B  [B,H,L,D]
  u16* Kb    = (u16*)(ws + 50331648);      //  8,388,608 B
  u16* Vb    = (u16*)(ws + 58720256);      //  8,388,608 B
  u16* AO    = (u16*)(ws + 67108864);      //  8,388,608 B  attn_out bf16 [4096][1024]

  k_cvt_x<<<4096, 256, 0, stream>>>(x, xb);
  k_transpose<<<dim3(96, 32), 256, 0, stream>>>(Wqkv, wqkvT, 1024, 3072);
  k_transpose<<<dim3(32, 32), 256, 0, stream>>>(Wo, woT, 1024, 1024);
  k_gemm<<<dim3(32, 24), 256, 0, stream>>>(xb, wqkvT, qkv, nullptr, 4096, 3072, 1024);
  k_normrope<<<16384, 256, 0, stream>>>(qkv, qw, kw, cosp, sinp, Qb, Kb, Vb);
  k_attn<<<dim3(32, 32), 256, 0, stream>>>(Qb, Kb, Vb, AO);
  k_gemm<<<dim3(32, 8), 256, 0, stream>>>(AO, woT, nullptr, out, 4096, 1024, 1024);
}

// Round 2
// 670.956 us; speedup vs baseline: 1.0366x; 1.0366x over previous
//
#include <hip/hip_runtime.h>

typedef __attribute__((ext_vector_type(8))) short bh8;   // 8 bf16 in 4 VGPRs
typedef __attribute__((ext_vector_type(4))) float f4;    // MFMA accumulator

typedef unsigned short u16;
typedef unsigned int u32;

__device__ inline u16 f2b(float f) {
  union { float f; u32 u; } v; v.f = f;
  u32 u = v.u;
  u32 r = (u + 0x7FFFu + ((u >> 16) & 1u)) >> 16;  // round-to-nearest-even
  return (u16)r;
}
__device__ inline float b2f(u16 b) {
  union { u32 u; float f; } v; v.u = ((u32)b) << 16;
  return v.f;
}

// async global->LDS, 16B per lane; LDS dest is wave-uniform base + lane*16
__device__ __forceinline__ void gload16(const u16* g, u16* l) {
  __builtin_amdgcn_global_load_lds(
      (__attribute__((address_space(1))) void*)(g),
      (__attribute__((address_space(3))) void*)(l),
      16, 0, 0);
}

// ---------------- prep: cast x to bf16 ----------------
__global__ __launch_bounds__(256) void k_cvt_x(const float* __restrict__ x,
                                               u16* __restrict__ xb) {
  int i = (blockIdx.x * 256 + threadIdx.x) * 4;
  float4 v = *(const float4*)&x[i];
  ushort4 o;
  o.x = f2b(v.x); o.y = f2b(v.y); o.z = f2b(v.z); o.w = f2b(v.w);
  *(ushort4*)&xb[i] = o;
}

// ---------------- prep: transpose weight (K x N f32) -> (N x K bf16) ----------------
__global__ __launch_bounds__(256) void k_transpose(const float* __restrict__ W,
                                                   u16* __restrict__ WT,
                                                   int K, int N) {
  __shared__ u16 t[32][33];
  int bx = blockIdx.x * 32, by = blockIdx.y * 32;
  int x = threadIdx.x & 31, y = threadIdx.x >> 5;  // y in 0..7
  for (int j = 0; j < 4; ++j) {
    int r = y + j * 8;
    t[r][x] = f2b(W[(size_t)(by + r) * N + bx + x]);
  }
  __syncthreads();
  for (int j = 0; j < 4; ++j) {
    int r = y + j * 8;
    WT[(size_t)(bx + r) * K + by + x] = t[x][r];  // WT[n][k] = W[k][n]
  }
}

// ---------------- GEMM (m97 structure): C[M,N] = A[M,K] * Bt[N,K], bf16 in ----------------
// 128x128 tile, BK=64, 4 waves (2x2), global_load_lds width=16, linear LDS.
__global__ __launch_bounds__(256) void k_gemm(const u16* __restrict__ A,
                                              const u16* __restrict__ Bt,
                                              u16* __restrict__ Cb,
                                              float* __restrict__ Cf,
                                              int M, int N, int K) {
  __shared__ u16 As[128 * 64];
  __shared__ u16 Bs[128 * 64];
  const int tid = threadIdx.x;
  const int lane = tid & 63, wid = tid >> 6;
  const int l15 = lane & 15, lg = lane >> 4;

  // bijective XCD swizzle (grid sizes here are multiples of 8)
  int nwg = gridDim.x * gridDim.y;
  int bid = blockIdx.y * gridDim.x + blockIdx.x;
  int cpx = nwg >> 3;
  int swz = (bid & 7) * cpx + (bid >> 3);
  int bx = swz % gridDim.x, by = swz / gridDim.x;
  const int bm = bx * 128, bn = by * 128;
  const int wr = (wid >> 1) * 64, wc = (wid & 1) * 64;

  f4 acc[4][4] = {};

  // per-lane source coords for staging: 8 lanes per 64-elem row
  const int srow = wid * 32 + (lane >> 3);
  const int scol = (lane & 7) * 8;

  for (int kb = 0; kb < K; kb += 64) {
    __syncthreads();  // previous iter's ds_reads done before overwrite
    {
      const u16* ga = A  + (size_t)(bm + srow) * K + kb + scol;
      const u16* gb = Bt + (size_t)(bn + srow) * K + kb + scol;
      u16* la = &As[(wid * 32) * 64];
      u16* lb = &Bs[(wid * 32) * 64];
      #pragma unroll
      for (int c = 0; c < 4; ++c) {
        gload16(ga, la);
        gload16(gb, lb);
        ga += (size_t)8 * K; gb += (size_t)8 * K;
        la += 8 * 64;        lb += 8 * 64;
      }
    }
    __syncthreads();  // compiler drains vmcnt(0) before barrier
    #pragma unroll
    for (int kk = 0; kk < 2; ++kk) {
      bh8 a[4], b[4];
      #pragma unroll
      for (int m = 0; m < 4; ++m)
        a[m] = *(const bh8*)&As[(wr + m * 16 + l15) * 64 + kk * 32 + lg * 8];
      #pragma unroll
      for (int n = 0; n < 4; ++n)
        b[n] = *(const bh8*)&Bs[(wc + n * 16 + l15) * 64 + kk * 32 + lg * 8];
      #pragma unroll
      for (int m = 0; m < 4; ++m)
        #pragma unroll
        for (int n = 0; n < 4; ++n)
          acc[m][n] = __builtin_amdgcn_mfma_f32_16x16x32_bf16(a[m], b[n], acc[m][n], 0, 0, 0);
    }
  }
  // D layout: col = lane&15, row = (lane>>4)*4 + reg   [m89-verified]
  for (int m = 0; m < 4; ++m)
    for (int n = 0; n < 4; ++n)
      for (int r = 0; r < 4; ++r) {
        int row = bm + wr + m * 16 + lg * 4 + r;
        int col = bn + wc + n * 16 + l15;
        float v = acc[m][n][r];
        if (Cf) Cf[(size_t)row * N + col] = v;
        else    Cb[(size_t)row * N + col] = f2b(v);
      }
}

// ---------------- RMSNorm + RoPE for Q,K; scatter -> Q/K [B,H,L,D] bf16 ----------------
__global__ __launch_bounds__(256) void k_normrope(const u16* __restrict__ qkv,
                                                  const float* __restrict__ qw,
                                                  const float* __restrict__ kw,
                                                  const float* __restrict__ cosp,
                                                  const float* __restrict__ sinp,
                                                  u16* __restrict__ Q,
                                                  u16* __restrict__ K) {
  int gw = blockIdx.x * 4 + (threadIdx.x >> 6);   // one wave per (b,l,h)
  int lane = threadIdx.x & 63;
  int h = gw & 15;
  int bl = gw >> 4;             // b*2048 + l
  int l = bl & 2047;
  int b = bl >> 11;
  const u16* base = qkv + (size_t)bl * 3072 + h * 64;
  float qv = b2f(base[lane]);
  float kv = b2f(base[1024 + lane]);
  float qs = qv * qv, ks = kv * kv;
  for (int off = 1; off < 64; off <<= 1) {
    qs += __shfl_xor(qs, off, 64);
    ks += __shfl_xor(ks, off, 64);
  }
  float qr = rsqrtf(qs * (1.0f / 64.0f) + 1e-6f);
  float kr = rsqrtf(ks * (1.0f / 64.0f) + 1e-6f);
  float qn = qv * qr * qw[lane];
  float kn = kv * kr * kw[lane];
  int d2 = lane & 31;
  float c = cosp[l * 32 + d2], s = sinp[l * 32 + d2];
  float qp = __shfl_xor(qn, 32, 64);
  float kp = __shfl_xor(kn, 32, 64);
  float qo = (lane < 32) ? (qn * c - qp * s) : (qp * s + qn * c);
  float ko = (lane < 32) ? (kn * c - kp * s) : (kp * s + kn * c);
  size_t oi = (size_t)((b * 16 + h) * 2048 + l) * 64 + lane;
  Q[oi] = f2b(qo);
  K[oi] = f2b(ko);
}

// ---------------- V transpose: qkv V-slice [B*L][HID] -> Vt [B,H,D=64,L=2048] ----------------
__global__ __launch_bounds__(256) void k_vtrans(const u16* __restrict__ qkv,
                                                u16* __restrict__ Vt) {
  __shared__ u16 t[32][33];
  int bh = blockIdx.z; int b = bh >> 4, h = bh & 15;
  int lb = blockIdx.x * 32, db = blockIdx.y * 32;
  int x = threadIdx.x & 31, y = threadIdx.x >> 5;
  const u16* src = qkv + (size_t)b * 2048 * 3072 + 2048 + h * 64;
  for (int j = 0; j < 4; ++j) {
    int r = y + j * 8;   // l offset within tile
    t[r][x] = src[(size_t)(lb + r) * 3072 + db + x];
  }
  __syncthreads();
  u16* dst = Vt + (size_t)bh * 64 * 2048;
  for (int j = 0; j < 4; ++j) {
    int r = y + j * 8;   // d offset within tile
    dst[(size_t)(db + r) * 2048 + lb + x] = t[x][r];
  }
}

// ---------------- flash attention, causal; V pre-transposed [D][L] ----------------
// grid: (L/64, B*H); 4 waves, wave handles 16 q rows; key tiles of 32.
__global__ __launch_bounds__(256) void k_attn(const u16* __restrict__ Q,
                                              const u16* __restrict__ K,
                                              const u16* __restrict__ Vt,
                                              u16* __restrict__ O) {
  int bh = blockIdx.y;
  int b = bh >> 4, h = bh & 15;
  int wid = threadIdx.x >> 6, lane = threadIdx.x & 63;
  int l15 = lane & 15, lg = lane >> 4;
  int qb = blockIdx.x * 64 + wid * 16;
  const u16* Qp = Q  + (size_t)bh * 2048 * 64;
  const u16* Kp = K  + (size_t)bh * 2048 * 64;
  const u16* Vp = Vt + (size_t)bh * 64 * 2048;
  __shared__ u16 P_lds[4][16][40];   // per-wave P tile [16 q][32 k]

  bh8 aq0 = *(const bh8*)&Qp[(size_t)(qb + l15) * 64 + lg * 8];
  bh8 aq1 = *(const bh8*)&Qp[(size_t)(qb + l15) * 64 + 32 + lg * 8];

  f4 acc[4] = {};          // out[16 q][64 d]: 4 d-tiles
  float mrow[4], lrow[4];
  for (int r = 0; r < 4; ++r) { mrow[r] = -1e30f; lrow[r] = 0.0f; }

  int nkt = (qb + 47) >> 5;      // covers keys 0..qb+15
  for (int kt = 0; kt < nkt; ++kt) {
    int kb = kt * 32;
    f4 s0 = {}, s1 = {};
    bh8 bk;
    bk = *(const bh8*)&Kp[(size_t)(kb + l15) * 64 + lg * 8];
    s0 = __builtin_amdgcn_mfma_f32_16x16x32_bf16(aq0, bk, s0, 0, 0, 0);
    bk = *(const bh8*)&Kp[(size_t)(kb + l15) * 64 + 32 + lg * 8];
    s0 = __builtin_amdgcn_mfma_f32_16x16x32_bf16(aq1, bk, s0, 0, 0, 0);
    bk = *(const bh8*)&Kp[(size_t)(kb + 16 + l15) * 64 + lg * 8];
    s1 = __builtin_amdgcn_mfma_f32_16x16x32_bf16(aq0, bk, s1, 0, 0, 0);
    bk = *(const bh8*)&Kp[(size_t)(kb + 16 + l15) * 64 + 32 + lg * 8];
    s1 = __builtin_amdgcn_mfma_f32_16x16x32_bf16(aq1, bk, s1, 0, 0, 0);

    float p0[4], p1[4], pm[4];
    for (int r = 0; r < 4; ++r) {
      int q = qb + lg * 4 + r;
      float v0 = s0[r] * 0.125f; if (kb + l15 > q)      v0 = -1e30f;
      float v1 = s1[r] * 0.125f; if (kb + 16 + l15 > q) v1 = -1e30f;
      p0[r] = v0; p1[r] = v1;
      pm[r] = fmaxf(v0, v1);
    }
    for (int off = 1; off < 16; off <<= 1)
      for (int r = 0; r < 4; ++r) pm[r] = fmaxf(pm[r], __shfl_xor(pm[r], off, 64));
    float fac[4], ps[4];
    for (int r = 0; r < 4; ++r) {
      float mnew = fmaxf(mrow[r], pm[r]);
      fac[r] = __expf(mrow[r] - mnew);
      mrow[r] = mnew;
      p0[r] = __expf(p0[r] - mnew);
      p1[r] = __expf(p1[r] - mnew);
      ps[r] = p0[r] + p1[r];
    }
    for (int off = 1; off < 16; off <<= 1)
      for (int r = 0; r < 4; ++r) ps[r] += __shfl_xor(ps[r], off, 64);
    for (int r = 0; r < 4; ++r) lrow[r] = lrow[r] * fac[r] + ps[r];
    for (int n = 0; n < 4; ++n)
      for (int r = 0; r < 4; ++r) acc[n][r] *= fac[r];

    // P (16x32) -> LDS in A-frag order
    for (int r = 0; r < 4; ++r) {
      P_lds[wid][lg * 4 + r][l15]      = f2b(p0[r]);
      P_lds[wid][lg * 4 + r][16 + l15] = f2b(p1[r]);
    }
    asm volatile("s_waitcnt lgkmcnt(0)" ::: "memory");
    bh8 pa = *(const bh8*)&P_lds[wid][l15][lg * 8];

    for (int n = 0; n < 4; ++n) {
      bh8 bv = *(const bh8*)&Vp[(size_t)(n * 16 + l15) * 2048 + kb + lg * 8];
      acc[n] = __builtin_amdgcn_mfma_f32_16x16x32_bf16(pa, bv, acc[n], 0, 0, 0);
    }
  }

  for (int n = 0; n < 4; ++n)
    for (int r = 0; r < 4; ++r) {
      int q = qb + lg * 4 + r;
      int d = n * 16 + l15;
      float o = acc[n][r] / lrow[r];
      O[((size_t)b * 2048 + q) * 1024 + h * 64 + d] = f2b(o);
    }
}

extern "C" void kernel_launch(void* const* d_in, const int* in_sizes, int n_in,
                              void* d_out, int out_size, void* d_ws, size_t ws_size,
                              hipStream_t stream) {
  (void)in_sizes; (void)n_in; (void)out_size; (void)ws_size;
  const float* x    = (const float*)d_in[0];
  const float* Wqkv = (const float*)d_in[1];
  const float* Wo   = (const float*)d_in[2];
  const float* qw   = (const float*)d_in[3];
  const float* kw   = (const float*)d_in[4];
  const float* cosp = (const float*)d_in[5];
  const float* sinp = (const float*)d_in[6];
  float* out = (float*)d_out;

  char* ws = (char*)d_ws;
  u16* xb    = (u16*)(ws);                 //  8,388,608 B  x bf16 [4096][1024]
  u16* wqkvT = (u16*)(ws + 8388608);       //  6,291,456 B  Wqkv^T bf16 [3072][1024]
  u16* woT   = (u16*)(ws + 14680064);      //  2,097,152 B  Wo^T bf16 [1024][1024]
  u16* qkv   = (u16*)(ws + 16777216);      // 25,165,824 B  qkv bf16 [4096][3072]
  u16* Qb    = (u16*)(ws + 41943040);      //  8,388,608 B  [B,H,L,D]
  u16* Kb    = (u16*)(ws + 50331648);      //  8,388,608 B
  u16* Vtb   = (u16*)(ws + 58720256);      //  8,388,608 B  [B,H,D,L]
  u16* AO    = (u16*)(ws + 67108864);      //  8,388,608 B  attn_out bf16 [4096][1024]

  k_cvt_x<<<4096, 256, 0, stream>>>(x, xb);
  k_transpose<<<dim3(96, 32), 256, 0, stream>>>(Wqkv, wqkvT, 1024, 3072);
  k_transpose<<<dim3(32, 32), 256, 0, stream>>>(Wo, woT, 1024, 1024);
  k_gemm<<<dim3(32, 24), 256, 0, stream>>>(xb, wqkvT, qkv, nullptr, 4096, 3072, 1024);
  k_normrope<<<16384, 256, 0, stream>>>(qkv, qw, kw, cosp, sinp, Qb, Kb);
  k_vtrans<<<dim3(64, 2, 32), 256, 0, stream>>>(qkv, Vtb);
  k_attn<<<dim3(32, 32), 256, 0, stream>>>(Qb, Kb, Vtb, AO);
  k_gemm<<<dim3(32, 8), 256, 0, stream>>>(AO, woT, nullptr, out, 4096, 1024, 1024);
}

// Round 3
// 327.349 us; speedup vs baseline: 2.1247x; 2.0497x over previous
//
#include <hip/hip_runtime.h>

typedef __attribute__((ext_vector_type(8))) short bh8;   // 8 bf16 in 4 VGPRs
typedef __attribute__((ext_vector_type(4))) float f4;    // MFMA accumulator

typedef unsigned short u16;
typedef unsigned int u32;

__device__ inline u16 f2b(float f) {
  union { float f; u32 u; } v; v.f = f;
  u32 u = v.u;
  u32 r = (u + 0x7FFFu + ((u >> 16) & 1u)) >> 16;  // round-to-nearest-even
  return (u16)r;
}
__device__ inline float b2f(u16 b) {
  union { u32 u; float f; } v; v.u = ((u32)b) << 16;
  return v.f;
}

// async global->LDS, 16B per lane; LDS dest is wave-uniform base + lane*16
__device__ __forceinline__ void gload16(const u16* g, u16* l) {
  __builtin_amdgcn_global_load_lds(
      (__attribute__((address_space(1))) void*)(g),
      (__attribute__((address_space(3))) void*)(l),
      16, 0, 0);
}

// ---------------- prep: cast x to bf16 ----------------
__global__ __launch_bounds__(256) void k_cvt_x(const float* __restrict__ x,
                                               u16* __restrict__ xb) {
  int i = (blockIdx.x * 256 + threadIdx.x) * 4;
  float4 v = *(const float4*)&x[i];
  ushort4 o;
  o.x = f2b(v.x); o.y = f2b(v.y); o.z = f2b(v.z); o.w = f2b(v.w);
  *(ushort4*)&xb[i] = o;
}

// ---------------- prep: transpose weight (K x N f32) -> (N x K bf16) ----------------
__global__ __launch_bounds__(256) void k_transpose(const float* __restrict__ W,
                                                   u16* __restrict__ WT,
                                                   int K, int N) {
  __shared__ u16 t[32][33];
  int bx = blockIdx.x * 32, by = blockIdx.y * 32;
  int x = threadIdx.x & 31, y = threadIdx.x >> 5;  // y in 0..7
  for (int j = 0; j < 4; ++j) {
    int r = y + j * 8;
    t[r][x] = f2b(W[(size_t)(by + r) * N + bx + x]);
  }
  __syncthreads();
  for (int j = 0; j < 4; ++j) {
    int r = y + j * 8;
    WT[(size_t)(bx + r) * K + by + x] = t[x][r];  // WT[n][k] = W[k][n]
  }
}

// ---------------- GEMM: C[M,N] = A[M,K] * Bt[N,K], bf16 in ----------------
// 128x128 tile, BK=64, 4 waves (2x2), double-buffered LDS, global_load_lds,
// 2-phase pipeline: stage(next) || compute(cur), ONE barrier per K-step.
template <bool F32OUT>
__global__ __launch_bounds__(256) void k_gemm(const u16* __restrict__ A,
                                              const u16* __restrict__ Bt,
                                              void* __restrict__ Cout,
                                              int M, int N, int K) {
  __shared__ u16 As[2][128 * 64];
  __shared__ u16 Bs[2][128 * 64];
  const int tid = threadIdx.x;
  const int lane = tid & 63, wid = tid >> 6;
  const int l15 = lane & 15, lg = lane >> 4;
  const int bm = blockIdx.x * 128, bn = blockIdx.y * 128;
  const int wr = (wid >> 1) * 64, wc = (wid & 1) * 64;

  f4 acc[4][4] = {};

  // per-lane staging source coords: 8 lanes per 64-elem row, wave covers 32 rows
  const int srow = wid * 32 + (lane >> 3);
  const int scol = (lane & 7) * 8;
  const u16* gA = A  + (size_t)(bm + srow) * K + scol;
  const u16* gB = Bt + (size_t)(bn + srow) * K + scol;

  const int nk = K >> 6;

  // prologue: stage tile 0 into buf 0
  {
    const u16* ga = gA; const u16* gb = gB;
    u16* la = &As[0][(wid * 32) * 64];
    u16* lb = &Bs[0][(wid * 32) * 64];
    #pragma unroll
    for (int c = 0; c < 4; ++c) {
      gload16(ga, la);
      gload16(gb, lb);
      ga += (size_t)8 * K; gb += (size_t)8 * K;
      la += 8 * 64;        lb += 8 * 64;
    }
  }
  __syncthreads();  // drains vmcnt(0): buf0 ready

  for (int t = 0; t < nk; ++t) {
    // issue next tile's loads into the other buffer (async, in flight during MFMA)
    if (t + 1 < nk) {
      int kb = (t + 1) << 6;
      const u16* ga = gA + kb; const u16* gb = gB + kb;
      u16* la = &As[(t + 1) & 1][(wid * 32) * 64];
      u16* lb = &Bs[(t + 1) & 1][(wid * 32) * 64];
      #pragma unroll
      for (int c = 0; c < 4; ++c) {
        gload16(ga, la);
        gload16(gb, lb);
        ga += (size_t)8 * K; gb += (size_t)8 * K;
        la += 8 * 64;        lb += 8 * 64;
      }
    }
    // compute on current buffer
    const u16* as = &As[t & 1][0];
    const u16* bs = &Bs[t & 1][0];
    #pragma unroll
    for (int kk = 0; kk < 2; ++kk) {
      bh8 a[4], b[4];
      #pragma unroll
      for (int m = 0; m < 4; ++m)
        a[m] = *(const bh8*)&as[(wr + m * 16 + l15) * 64 + kk * 32 + lg * 8];
      #pragma unroll
      for (int n = 0; n < 4; ++n)
        b[n] = *(const bh8*)&bs[(wc + n * 16 + l15) * 64 + kk * 32 + lg * 8];
      #pragma unroll
      for (int m = 0; m < 4; ++m)
        #pragma unroll
        for (int n = 0; n < 4; ++n)
          acc[m][n] = __builtin_amdgcn_mfma_f32_16x16x32_bf16(a[m], b[n], acc[m][n], 0, 0, 0);
    }
    // one barrier per K-step: drains vmcnt(0) (next buf written by all waves)
    // and lgkmcnt, and protects cur buf from next iteration's overwrite.
    __syncthreads();
  }

  // D layout: col = lane&15, row = (lane>>4)*4 + reg   [m89-verified]
  for (int m = 0; m < 4; ++m)
    for (int n = 0; n < 4; ++n)
      for (int r = 0; r < 4; ++r) {
        int row = bm + wr + m * 16 + lg * 4 + r;
        int col = bn + wc + n * 16 + l15;
        float v = acc[m][n][r];
        if constexpr (F32OUT) ((float*)Cout)[(size_t)row * N + col] = v;
        else                  ((u16*)Cout)[(size_t)row * N + col]  = f2b(v);
      }
}

// ---------------- RMSNorm + RoPE for Q,K; scatter -> Q/K [B,H,L,D] bf16 ----------------
__global__ __launch_bounds__(256) void k_normrope(const u16* __restrict__ qkv,
                                                  const float* __restrict__ qw,
                                                  const float* __restrict__ kw,
                                                  const float* __restrict__ cosp,
                                                  const float* __restrict__ sinp,
                                                  u16* __restrict__ Q,
                                                  u16* __restrict__ K) {
  int gw = blockIdx.x * 4 + (threadIdx.x >> 6);   // one wave per (b,l,h)
  int lane = threadIdx.x & 63;
  int h = gw & 15;
  int bl = gw >> 4;             // b*2048 + l
  int l = bl & 2047;
  int b = bl >> 11;
  const u16* base = qkv + (size_t)bl * 3072 + h * 64;
  float qv = b2f(base[lane]);
  float kv = b2f(base[1024 + lane]);
  float qs = qv * qv, ks = kv * kv;
  for (int off = 1; off < 64; off <<= 1) {
    qs += __shfl_xor(qs, off, 64);
    ks += __shfl_xor(ks, off, 64);
  }
  float qr = rsqrtf(qs * (1.0f / 64.0f) + 1e-6f);
  float kr = rsqrtf(ks * (1.0f / 64.0f) + 1e-6f);
  float qn = qv * qr * qw[lane];
  float kn = kv * kr * kw[lane];
  int d2 = lane & 31;
  float c = cosp[l * 32 + d2], s = sinp[l * 32 + d2];
  float qp = __shfl_xor(qn, 32, 64);
  float kp = __shfl_xor(kn, 32, 64);
  float qo = (lane < 32) ? (qn * c - qp * s) : (qp * s + qn * c);
  float ko = (lane < 32) ? (kn * c - kp * s) : (kp * s + kn * c);
  size_t oi = (size_t)((b * 16 + h) * 2048 + l) * 64 + lane;
  Q[oi] = f2b(qo);
  K[oi] = f2b(ko);
}

// ---------------- V transpose: qkv V-slice [B*L][HID] -> Vt [B,H,D=64,L=2048] ----------------
__global__ __launch_bounds__(256) void k_vtrans(const u16* __restrict__ qkv,
                                                u16* __restrict__ Vt) {
  __shared__ u16 t[32][33];
  int bh = blockIdx.z; int b = bh >> 4, h = bh & 15;
  int lb = blockIdx.x * 32, db = blockIdx.y * 32;
  int x = threadIdx.x & 31, y = threadIdx.x >> 5;
  const u16* src = qkv + (size_t)b * 2048 * 3072 + 2048 + h * 64;
  for (int j = 0; j < 4; ++j) {
    int r = y + j * 8;   // l offset within tile
    t[r][x] = src[(size_t)(lb + r) * 3072 + db + x];
  }
  __syncthreads();
  u16* dst = Vt + (size_t)bh * 64 * 2048;
  for (int j = 0; j < 4; ++j) {
    int r = y + j * 8;   // d offset within tile
    dst[(size_t)(db + r) * 2048 + lb + x] = t[x][r];
  }
}

// ---------------- flash attention, causal; V pre-transposed [D][L] ----------------
// grid: (L/64, B*H); 4 waves, wave handles 16 q rows; key tiles of 32.
__global__ __launch_bounds__(256) void k_attn(const u16* __restrict__ Q,
                                              const u16* __restrict__ K,
                                              const u16* __restrict__ Vt,
                                              u16* __restrict__ O) {
  int bh = blockIdx.y;
  int b = bh >> 4, h = bh & 15;
  int wid = threadIdx.x >> 6, lane = threadIdx.x & 63;
  int l15 = lane & 15, lg = lane >> 4;
  int qb = blockIdx.x * 64 + wid * 16;
  const u16* Qp = Q  + (size_t)bh * 2048 * 64;
  const u16* Kp = K  + (size_t)bh * 2048 * 64;
  const u16* Vp = Vt + (size_t)bh * 64 * 2048;
  __shared__ u16 P_lds[4][16][40];   // per-wave P tile [16 q][32 k]

  bh8 aq0 = *(const bh8*)&Qp[(size_t)(qb + l15) * 64 + lg * 8];
  bh8 aq1 = *(const bh8*)&Qp[(size_t)(qb + l15) * 64 + 32 + lg * 8];

  f4 acc[4] = {};          // out[16 q][64 d]: 4 d-tiles
  float mrow[4], lrow[4];
  for (int r = 0; r < 4; ++r) { mrow[r] = -1e30f; lrow[r] = 0.0f; }

  int nkt = (qb + 47) >> 5;      // covers keys 0..qb+15
  for (int kt = 0; kt < nkt; ++kt) {
    int kb = kt * 32;
    f4 s0 = {}, s1 = {};
    bh8 bk;
    bk = *(const bh8*)&Kp[(size_t)(kb + l15) * 64 + lg * 8];
    s0 = __builtin_amdgcn_mfma_f32_16x16x32_bf16(aq0, bk, s0, 0, 0, 0);
    bk = *(const bh8*)&Kp[(size_t)(kb + l15) * 64 + 32 + lg * 8];
    s0 = __builtin_amdgcn_mfma_f32_16x16x32_bf16(aq1, bk, s0, 0, 0, 0);
    bk = *(const bh8*)&Kp[(size_t)(kb + 16 + l15) * 64 + lg * 8];
    s1 = __builtin_amdgcn_mfma_f32_16x16x32_bf16(aq0, bk, s1, 0, 0, 0);
    bk = *(const bh8*)&Kp[(size_t)(kb + 16 + l15) * 64 + 32 + lg * 8];
    s1 = __builtin_amdgcn_mfma_f32_16x16x32_bf16(aq1, bk, s1, 0, 0, 0);

    float p0[4], p1[4], pm[4];
    for (int r = 0; r < 4; ++r) {
      int q = qb + lg * 4 + r;
      float v0 = s0[r] * 0.125f; if (kb + l15 > q)      v0 = -1e30f;
      float v1 = s1[r] * 0.125f; if (kb + 16 + l15 > q) v1 = -1e30f;
      p0[r] = v0; p1[r] = v1;
      pm[r] = fmaxf(v0, v1);
    }
    for (int off = 1; off < 16; off <<= 1)
      for (int r = 0; r < 4; ++r) pm[r] = fmaxf(pm[r], __shfl_xor(pm[r], off, 64));
    float fac[4], ps[4];
    for (int r = 0; r < 4; ++r) {
      float mnew = fmaxf(mrow[r], pm[r]);
      fac[r] = __expf(mrow[r] - mnew);
      mrow[r] = mnew;
      p0[r] = __expf(p0[r] - mnew);
      p1[r] = __expf(p1[r] - mnew);
      ps[r] = p0[r] + p1[r];
    }
    for (int off = 1; off < 16; off <<= 1)
      for (int r = 0; r < 4; ++r) ps[r] += __shfl_xor(ps[r], off, 64);
    for (int r = 0; r < 4; ++r) lrow[r] = lrow[r] * fac[r] + ps[r];
    for (int n = 0; n < 4; ++n)
      for (int r = 0; r < 4; ++r) acc[n][r] *= fac[r];

    // P (16x32) -> LDS in A-frag order
    for (int r = 0; r < 4; ++r) {
      P_lds[wid][lg * 4 + r][l15]      = f2b(p0[r]);
      P_lds[wid][lg * 4 + r][16 + l15] = f2b(p1[r]);
    }
    asm volatile("s_waitcnt lgkmcnt(0)" ::: "memory");
    bh8 pa = *(const bh8*)&P_lds[wid][l15][lg * 8];

    for (int n = 0; n < 4; ++n) {
      bh8 bv = *(const bh8*)&Vp[(size_t)(n * 16 + l15) * 2048 + kb + lg * 8];
      acc[n] = __builtin_amdgcn_mfma_f32_16x16x32_bf16(pa, bv, acc[n], 0, 0, 0);
    }
  }

  for (int n = 0; n < 4; ++n)
    for (int r = 0; r < 4; ++r) {
      int q = qb + lg * 4 + r;
      int d = n * 16 + l15;
      float o = acc[n][r] / lrow[r];
      O[((size_t)b * 2048 + q) * 1024 + h * 64 + d] = f2b(o);
    }
}

extern "C" void kernel_launch(void* const* d_in, const int* in_sizes, int n_in,
                              void* d_out, int out_size, void* d_ws, size_t ws_size,
                              hipStream_t stream) {
  (void)in_sizes; (void)n_in; (void)out_size; (void)ws_size;
  const float* x    = (const float*)d_in[0];
  const float* Wqkv = (const float*)d_in[1];
  const float* Wo   = (const float*)d_in[2];
  const float* qw   = (const float*)d_in[3];
  const float* kw   = (const float*)d_in[4];
  const float* cosp = (const float*)d_in[5];
  const float* sinp = (const float*)d_in[6];
  float* out = (float*)d_out;

  char* ws = (char*)d_ws;
  u16* xb    = (u16*)(ws);                 //  8,388,608 B  x bf16 [4096][1024]
  u16* wqkvT = (u16*)(ws + 8388608);       //  6,291,456 B  Wqkv^T bf16 [3072][1024]
  u16* woT   = (u16*)(ws + 14680064);      //  2,097,152 B  Wo^T bf16 [1024][1024]
  u16* qkv   = (u16*)(ws + 16777216);      // 25,165,824 B  qkv bf16 [4096][3072]
  u16* Qb    = (u16*)(ws + 41943040);      //  8,388,608 B  [B,H,L,D]
  u16* Kb    = (u16*)(ws + 50331648);      //  8,388,608 B
  u16* Vtb   = (u16*)(ws + 58720256);      //  8,388,608 B  [B,H,D,L]
  u16* AO    = (u16*)(ws + 67108864);      //  8,388,608 B  attn_out bf16 [4096][1024]

  k_cvt_x<<<4096, 256, 0, stream>>>(x, xb);
  k_transpose<<<dim3(96, 32), 256, 0, stream>>>(Wqkv, wqkvT, 1024, 3072);
  k_transpose<<<dim3(32, 32), 256, 0, stream>>>(Wo, woT, 1024, 1024);
  k_gemm<false><<<dim3(32, 24), 256, 0, stream>>>(xb, wqkvT, qkv, 4096, 3072, 1024);
  k_normrope<<<16384, 256, 0, stream>>>(qkv, qw, kw, cosp, sinp, Qb, Kb);
  k_vtrans<<<dim3(64, 2, 32), 256, 0, stream>>>(qkv, Vtb);
  k_attn<<<dim3(32, 32), 256, 0, stream>>>(Qb, Kb, Vtb, AO);
  k_gemm<true><<<dim3(32, 8), 256, 0, stream>>>(AO, woT, out, 4096, 1024, 1024);
}

// Round 4
// 182.072 us; speedup vs baseline: 3.8199x; 1.7979x over previous
//
#include <hip/hip_runtime.h>

typedef __attribute__((ext_vector_type(8))) short bh8;   // 8 bf16 in 4 VGPRs
typedef __attribute__((ext_vector_type(4))) float f4;    // MFMA accumulator

typedef unsigned short u16;
typedef unsigned int u32;

__device__ inline u16 f2b(float f) {
  union { float f; u32 u; } v; v.f = f;
  u32 u = v.u;
  u32 r = (u + 0x7FFFu + ((u >> 16) & 1u)) >> 16;  // round-to-nearest-even
  return (u16)r;
}
__device__ inline float b2f(u16 b) {
  union { u32 u; float f; } v; v.u = ((u32)b) << 16;
  return v.f;
}

// async global->LDS, 16B per lane; LDS dest is wave-uniform base + lane*16
__device__ __forceinline__ void gload16(const u16* g, u16* l) {
  __builtin_amdgcn_global_load_lds(
      (__attribute__((address_space(1))) void*)(g),
      (__attribute__((address_space(3))) void*)(l),
      16, 0, 0);
}

// ---------------- prep: cast x to bf16 ----------------
__global__ __launch_bounds__(256) void k_cvt_x(const float* __restrict__ x,
                                               u16* __restrict__ xb) {
  int i = (blockIdx.x * 256 + threadIdx.x) * 4;
  float4 v = *(const float4*)&x[i];
  ushort4 o;
  o.x = f2b(v.x); o.y = f2b(v.y); o.z = f2b(v.z); o.w = f2b(v.w);
  *(ushort4*)&xb[i] = o;
}

// ---------------- prep: transpose weight (K x N f32) -> (N x K bf16) ----------------
__global__ __launch_bounds__(256) void k_transpose(const float* __restrict__ W,
                                                   u16* __restrict__ WT,
                                                   int K, int N) {
  __shared__ u16 t[32][33];
  int bx = blockIdx.x * 32, by = blockIdx.y * 32;
  int x = threadIdx.x & 31, y = threadIdx.x >> 5;  // y in 0..7
  for (int j = 0; j < 4; ++j) {
    int r = y + j * 8;
    t[r][x] = f2b(W[(size_t)(by + r) * N + bx + x]);
  }
  __syncthreads();
  for (int j = 0; j < 4; ++j) {
    int r = y + j * 8;
    WT[(size_t)(bx + r) * K + by + x] = t[x][r];  // WT[n][k] = W[k][n]
  }
}

// ---------------- GEMM: C[M,N] = A[M,K] * Bt[N,K], bf16 in ----------------
// 128x128 tile, BK=64, 4 waves (2x2), double-buffered LDS, global_load_lds,
// 2-phase pipeline: stage(next) || compute(cur), ONE barrier per K-step.
template <bool F32OUT>
__global__ __launch_bounds__(256) void k_gemm(const u16* __restrict__ A,
                                              const u16* __restrict__ Bt,
                                              void* __restrict__ Cout,
                                              int M, int N, int K) {
  __shared__ u16 As[2][128 * 64];
  __shared__ u16 Bs[2][128 * 64];
  const int tid = threadIdx.x;
  const int lane = tid & 63, wid = tid >> 6;
  const int l15 = lane & 15, lg = lane >> 4;
  const int bm = blockIdx.x * 128, bn = blockIdx.y * 128;
  const int wr = (wid >> 1) * 64, wc = (wid & 1) * 64;

  f4 acc[4][4] = {};

  const int srow = wid * 32 + (lane >> 3);
  const int scol = (lane & 7) * 8;
  const u16* gA = A  + (size_t)(bm + srow) * K + scol;
  const u16* gB = Bt + (size_t)(bn + srow) * K + scol;

  const int nk = K >> 6;

  {
    const u16* ga = gA; const u16* gb = gB;
    u16* la = &As[0][(wid * 32) * 64];
    u16* lb = &Bs[0][(wid * 32) * 64];
    #pragma unroll
    for (int c = 0; c < 4; ++c) {
      gload16(ga, la);
      gload16(gb, lb);
      ga += (size_t)8 * K; gb += (size_t)8 * K;
      la += 8 * 64;        lb += 8 * 64;
    }
  }
  __syncthreads();

  for (int t = 0; t < nk; ++t) {
    if (t + 1 < nk) {
      int kb = (t + 1) << 6;
      const u16* ga = gA + kb; const u16* gb = gB + kb;
      u16* la = &As[(t + 1) & 1][(wid * 32) * 64];
      u16* lb = &Bs[(t + 1) & 1][(wid * 32) * 64];
      #pragma unroll
      for (int c = 0; c < 4; ++c) {
        gload16(ga, la);
        gload16(gb, lb);
        ga += (size_t)8 * K; gb += (size_t)8 * K;
        la += 8 * 64;        lb += 8 * 64;
      }
    }
    const u16* as = &As[t & 1][0];
    const u16* bs = &Bs[t & 1][0];
    #pragma unroll
    for (int kk = 0; kk < 2; ++kk) {
      bh8 a[4], b[4];
      #pragma unroll
      for (int m = 0; m < 4; ++m)
        a[m] = *(const bh8*)&as[(wr + m * 16 + l15) * 64 + kk * 32 + lg * 8];
      #pragma unroll
      for (int n = 0; n < 4; ++n)
        b[n] = *(const bh8*)&bs[(wc + n * 16 + l15) * 64 + kk * 32 + lg * 8];
      #pragma unroll
      for (int m = 0; m < 4; ++m)
        #pragma unroll
        for (int n = 0; n < 4; ++n)
          acc[m][n] = __builtin_amdgcn_mfma_f32_16x16x32_bf16(a[m], b[n], acc[m][n], 0, 0, 0);
    }
    __syncthreads();
  }

  for (int m = 0; m < 4; ++m)
    for (int n = 0; n < 4; ++n)
      for (int r = 0; r < 4; ++r) {
        int row = bm + wr + m * 16 + lg * 4 + r;
        int col = bn + wc + n * 16 + l15;
        float v = acc[m][n][r];
        if constexpr (F32OUT) ((float*)Cout)[(size_t)row * N + col] = v;
        else                  ((u16*)Cout)[(size_t)row * N + col]  = f2b(v);
      }
}

// ---------------- RMSNorm + RoPE for Q,K; scatter -> Q/K [B,H,L,D] bf16 ----------------
__global__ __launch_bounds__(256) void k_normrope(const u16* __restrict__ qkv,
                                                  const float* __restrict__ qw,
                                                  const float* __restrict__ kw,
                                                  const float* __restrict__ cosp,
                                                  const float* __restrict__ sinp,
                                                  u16* __restrict__ Q,
                                                  u16* __restrict__ K) {
  int gw = blockIdx.x * 4 + (threadIdx.x >> 6);   // one wave per (b,l,h)
  int lane = threadIdx.x & 63;
  int h = gw & 15;
  int bl = gw >> 4;             // b*2048 + l
  int l = bl & 2047;
  int b = bl >> 11;
  const u16* base = qkv + (size_t)bl * 3072 + h * 64;
  float qv = b2f(base[lane]);
  float kv = b2f(base[1024 + lane]);
  float qs = qv * qv, ks = kv * kv;
  for (int off = 1; off < 64; off <<= 1) {
    qs += __shfl_xor(qs, off, 64);
    ks += __shfl_xor(ks, off, 64);
  }
  float qr = rsqrtf(qs * (1.0f / 64.0f) + 1e-6f);
  float kr = rsqrtf(ks * (1.0f / 64.0f) + 1e-6f);
  float qn = qv * qr * qw[lane];
  float kn = kv * kr * kw[lane];
  int d2 = lane & 31;
  float c = cosp[l * 32 + d2], s = sinp[l * 32 + d2];
  float qp = __shfl_xor(qn, 32, 64);
  float kp = __shfl_xor(kn, 32, 64);
  float qo = (lane < 32) ? (qn * c - qp * s) : (qp * s + qn * c);
  float ko = (lane < 32) ? (kn * c - kp * s) : (kp * s + kn * c);
  size_t oi = (size_t)((b * 16 + h) * 2048 + l) * 64 + lane;
  Q[oi] = f2b(qo);
  K[oi] = f2b(ko);
}

// ---------------- V transpose: qkv V-slice [B*L][HID] -> Vt [B,H,D=64,L=2048] ----------------
__global__ __launch_bounds__(256) void k_vtrans(const u16* __restrict__ qkv,
                                                u16* __restrict__ Vt) {
  __shared__ u16 t[32][33];
  int bh = blockIdx.z; int b = bh >> 4, h = bh & 15;
  int lb = blockIdx.x * 32, db = blockIdx.y * 32;
  int x = threadIdx.x & 31, y = threadIdx.x >> 5;
  const u16* src = qkv + (size_t)b * 2048 * 3072 + 2048 + h * 64;
  for (int j = 0; j < 4; ++j) {
    int r = y + j * 8;   // l offset within tile
    t[r][x] = src[(size_t)(lb + r) * 3072 + db + x];
  }
  __syncthreads();
  u16* dst = Vt + (size_t)bh * 64 * 2048;
  for (int j = 0; j < 4; ++j) {
    int r = y + j * 8;   // d offset within tile
    dst[(size_t)(db + r) * 2048 + lb + x] = t[x][r];
  }
}

// ---------------- flash attention, causal; swapped-MFMA m214-style ----------------
// grid: (16, B*H); 4 waves x 32 q-rows = 128 q-rows per block; KVBLK=64.
// K/V staged in LDS (double-buffered, global_load_lds, XOR chunk swizzle).
// QK^T computed as mfma(K,Q) -> S^T (col=q); PV as mfma(V^T,P) (col=q), so
// online-softmax m/l/fac are lane-local to the accumulator columns.
__global__ __launch_bounds__(256, 3) void k_attn(const u16* __restrict__ Q,
                                                 const u16* __restrict__ K,
                                                 const u16* __restrict__ Vt,
                                                 u16* __restrict__ O) {
  __shared__ u16 Ks[2][64 * 64];   // [k-local][d], XOR-swizzled chunks
  __shared__ u16 Vs[2][64 * 64];   // [d][k-local], XOR-swizzled chunks
  __shared__ u16 Pl[4][32][80];    // per-wave P [q-local][k-local], pad 80

  const int bh = blockIdx.y;
  const int b = bh >> 4, h = bh & 15;
  const int wid = threadIdx.x >> 6, lane = threadIdx.x & 63;
  const int l15 = lane & 15, lg = lane >> 4;
  const int qt = 15 - (int)blockIdx.x;       // LPT: longest blocks first
  const int qb = qt * 128 + wid * 32;

  const u16* Qp = Q  + (size_t)bh * 2048 * 64;
  const u16* Kp = K  + (size_t)bh * 2048 * 64;
  const u16* Vp = Vt + (size_t)bh * 64 * 2048;

  // staging coords: thread covers rows sr0 and sr0+32, chunk sc (of 8)
  const int sr0 = wid * 8 + (lane >> 3);
  const int sc  = lane & 7;

  // hoisted Q fragments (B-operand: col=l15=q, k=lg*8+j over d)
  bh8 aq[2][2];
  #pragma unroll
  for (int qi = 0; qi < 2; ++qi)
    #pragma unroll
    for (int hh = 0; hh < 2; ++hh)
      aq[qi][hh] = *(const bh8*)&Qp[(size_t)(qb + qi * 16 + l15) * 64 + hh * 32 + lg * 8];

  f4 acc[2][4] = {};                 // O^T frags: acc[qi][n], col=q, row=d
  float mrow[2] = {-1e30f, -1e30f};
  float lrow[2] = {0.0f, 0.0f};

  const int nkt  = qt * 2 + 2;       // tiles needed by the whole block
  const int tmax = (qb + 31) >> 6;   // last tile this wave needs

  // prologue: stage tile 0
  {
    int r0 = sr0, r1 = 32 + sr0;
    gload16(Kp + (size_t)r0 * 64   + (size_t)((sc ^ (r0 & 7)) * 8), &Ks[0][(wid * 8) * 64]);
    gload16(Kp + (size_t)r1 * 64   + (size_t)((sc ^ (r1 & 7)) * 8), &Ks[0][(32 + wid * 8) * 64]);
    gload16(Vp + (size_t)r0 * 2048 + (size_t)((sc ^ (r0 & 7)) * 8), &Vs[0][(wid * 8) * 64]);
    gload16(Vp + (size_t)r1 * 2048 + (size_t)((sc ^ (r1 & 7)) * 8), &Vs[0][(32 + wid * 8) * 64]);
  }
  __syncthreads();

  for (int t = 0; t < nkt; ++t) {
    // stage next tile into other buffer (in flight under compute)
    if (t + 1 < nkt) {
      int kb = (t + 1) * 64;
      int nb = (t + 1) & 1;
      int r0 = sr0, r1 = 32 + sr0;
      gload16(Kp + (size_t)(kb + r0) * 64 + (size_t)((sc ^ (r0 & 7)) * 8), &Ks[nb][(wid * 8) * 64]);
      gload16(Kp + (size_t)(kb + r1) * 64 + (size_t)((sc ^ (r1 & 7)) * 8), &Ks[nb][(32 + wid * 8) * 64]);
      gload16(Vp + (size_t)r0 * 2048 + kb + (size_t)((sc ^ (r0 & 7)) * 8), &Vs[nb][(wid * 8) * 64]);
      gload16(Vp + (size_t)r1 * 2048 + kb + (size_t)((sc ^ (r1 & 7)) * 8), &Vs[nb][(32 + wid * 8) * 64]);
    }
    if (t <= tmax) {
      const int kb = t * 64;
      const u16* ks = &Ks[t & 1][0];
      const u16* vs = &Vs[t & 1][0];

      // ---- QK^T (swapped): s[kq][qi] = K-tile x Q^T, D col=q ----
      f4 s[4][2] = {};
      #pragma unroll
      for (int kq = 0; kq < 4; ++kq) {
        int row = kq * 16 + l15;
        int cs = row & 7;
        bh8 ka0 = *(const bh8*)&ks[row * 64 + ((0 + lg) ^ cs) * 8];
        bh8 ka1 = *(const bh8*)&ks[row * 64 + ((4 + lg) ^ cs) * 8];
        #pragma unroll
        for (int qi = 0; qi < 2; ++qi) {
          s[kq][qi] = __builtin_amdgcn_mfma_f32_16x16x32_bf16(ka0, aq[qi][0], s[kq][qi], 0, 0, 0);
          s[kq][qi] = __builtin_amdgcn_mfma_f32_16x16x32_bf16(ka1, aq[qi][1], s[kq][qi], 0, 0, 0);
        }
      }

      // ---- online softmax: k-axis in-lane (16 vals) + 2 shuffles ----
      float p[4][2][4];
      #pragma unroll
      for (int qi = 0; qi < 2; ++qi) {
        int q = qb + qi * 16 + l15;
        float mx = -1e30f;
        #pragma unroll
        for (int kq = 0; kq < 4; ++kq)
          #pragma unroll
          for (int r = 0; r < 4; ++r) {
            int k = kb + kq * 16 + lg * 4 + r;
            float v = (k <= q) ? s[kq][qi][r] * 0.125f : -1e30f;
            p[kq][qi][r] = v;
            mx = fmaxf(mx, v);
          }
        mx = fmaxf(mx, __shfl_xor(mx, 16, 64));
        mx = fmaxf(mx, __shfl_xor(mx, 32, 64));
        float mnew = fmaxf(mrow[qi], mx);
        float fac = __expf(mrow[qi] - mnew);
        mrow[qi] = mnew;
        float ps = 0.0f;
        #pragma unroll
        for (int kq = 0; kq < 4; ++kq)
          #pragma unroll
          for (int r = 0; r < 4; ++r) {
            float e = __expf(p[kq][qi][r] - mnew);
            p[kq][qi][r] = e;
            ps += e;
          }
        ps += __shfl_xor(ps, 16, 64);
        ps += __shfl_xor(ps, 32, 64);
        lrow[qi] = lrow[qi] * fac + ps;
        #pragma unroll
        for (int n = 0; n < 4; ++n)
          #pragma unroll
          for (int r = 0; r < 4; ++r) acc[qi][n][r] *= fac;
      }

      // ---- P -> per-wave LDS [q][k] ----
      #pragma unroll
      for (int qi = 0; qi < 2; ++qi)
        #pragma unroll
        for (int kq = 0; kq < 4; ++kq) {
          ushort4 w4;
          w4.x = f2b(p[kq][qi][0]); w4.y = f2b(p[kq][qi][1]);
          w4.z = f2b(p[kq][qi][2]); w4.w = f2b(p[kq][qi][3]);
          *(ushort4*)&Pl[wid][qi * 16 + l15][kq * 16 + lg * 4] = w4;
        }
      asm volatile("s_waitcnt lgkmcnt(0)" ::: "memory");
      __builtin_amdgcn_sched_barrier(0);

      // ---- PV (double-swapped): acc[qi][n] += V^T-frag x P-frag, D col=q ----
      #pragma unroll
      for (int g = 0; g < 2; ++g) {
        bh8 pb0 = *(const bh8*)&Pl[wid][l15][g * 32 + lg * 8];
        bh8 pb1 = *(const bh8*)&Pl[wid][16 + l15][g * 32 + lg * 8];
        #pragma unroll
        for (int n = 0; n < 4; ++n) {
          int row = n * 16 + l15;
          bh8 va = *(const bh8*)&vs[row * 64 + (((g * 4 + lg) ^ (row & 7)) * 8)];
          acc[0][n] = __builtin_amdgcn_mfma_f32_16x16x32_bf16(va, pb0, acc[0][n], 0, 0, 0);
          acc[1][n] = __builtin_amdgcn_mfma_f32_16x16x32_bf16(va, pb1, acc[1][n], 0, 0, 0);
        }
      }
    }
    __syncthreads();
  }

  // epilogue: acc col=q (l15), row=d (lg*4+r) -> 4 consecutive d per reg-quad
  #pragma unroll
  for (int qi = 0; qi < 2; ++qi) {
    float inv = 1.0f / lrow[qi];
    int q = qb + qi * 16 + l15;
    #pragma unroll
    for (int n = 0; n < 4; ++n) {
      ushort4 w4;
      w4.x = f2b(acc[qi][n][0] * inv);
      w4.y = f2b(acc[qi][n][1] * inv);
      w4.z = f2b(acc[qi][n][2] * inv);
      w4.w = f2b(acc[qi][n][3] * inv);
      *(ushort4*)&O[((size_t)b * 2048 + q) * 1024 + h * 64 + n * 16 + lg * 4] = w4;
    }
  }
}

extern "C" void kernel_launch(void* const* d_in, const int* in_sizes, int n_in,
                              void* d_out, int out_size, void* d_ws, size_t ws_size,
                              hipStream_t stream) {
  (void)in_sizes; (void)n_in; (void)out_size; (void)ws_size;
  const float* x    = (const float*)d_in[0];
  const float* Wqkv = (const float*)d_in[1];
  const float* Wo   = (const float*)d_in[2];
  const float* qw   = (const float*)d_in[3];
  const float* kw   = (const float*)d_in[4];
  const float* cosp = (const float*)d_in[5];
  const float* sinp = (const float*)d_in[6];
  float* out = (float*)d_out;

  char* ws = (char*)d_ws;
  u16* xb    = (u16*)(ws);                 //  8,388,608 B  x bf16 [4096][1024]
  u16* wqkvT = (u16*)(ws + 8388608);       //  6,291,456 B  Wqkv^T bf16 [3072][1024]
  u16* woT   = (u16*)(ws + 14680064);      //  2,097,152 B  Wo^T bf16 [1024][1024]
  u16* qkv   = (u16*)(ws + 16777216);      // 25,165,824 B  qkv bf16 [4096][3072]
  u16* Qb    = (u16*)(ws + 41943040);      //  8,388,608 B  [B,H,L,D]
  u16* Kb    = (u16*)(ws + 50331648);      //  8,388,608 B
  u16* Vtb   = (u16*)(ws + 58720256);      //  8,388,608 B  [B,H,D,L]
  u16* AO    = (u16*)(ws + 67108864);      //  8,388,608 B  attn_out bf16 [4096][1024]

  k_cvt_x<<<4096, 256, 0, stream>>>(x, xb);
  k_transpose<<<dim3(96, 32), 256, 0, stream>>>(Wqkv, wqkvT, 1024, 3072);
  k_transpose<<<dim3(32, 32), 256, 0, stream>>>(Wo, woT, 1024, 1024);
  k_gemm<false><<<dim3(32, 24), 256, 0, stream>>>(xb, wqkvT, qkv, 4096, 3072, 1024);
  k_normrope<<<16384, 256, 0, stream>>>(qkv, qw, kw, cosp, sinp, Qb, Kb);
  k_vtrans<<<dim3(64, 2, 32), 256, 0, stream>>>(qkv, Vtb);
  k_attn<<<dim3(16, 32), 256, 0, stream>>>(Qb, Kb, Vtb, AO);
  k_gemm<true><<<dim3(32, 8), 256, 0, stream>>>(AO, woT, out, 4096, 1024, 1024);
}

// Round 5
// 172.935 us; speedup vs baseline: 4.0218x; 1.0528x over previous
//
#include <hip/hip_runtime.h>

typedef __attribute__((ext_vector_type(8))) short bh8;   // 8 bf16 in 4 VGPRs
typedef __attribute__((ext_vector_type(4))) float f4;    // MFMA accumulator

typedef unsigned short u16;
typedef unsigned int u32;

__device__ inline u16 f2b(float f) {
  union { float f; u32 u; } v; v.f = f;
  u32 u = v.u;
  u32 r = (u + 0x7FFFu + ((u >> 16) & 1u)) >> 16;  // round-to-nearest-even
  return (u16)r;
}
__device__ inline float b2f(u16 b) {
  union { u32 u; float f; } v; v.u = ((u32)b) << 16;
  return v.f;
}

// async global->LDS, 16B per lane; LDS dest is wave-uniform base + lane*16
__device__ __forceinline__ void gload16(const u16* g, u16* l) {
  __builtin_amdgcn_global_load_lds(
      (__attribute__((address_space(1))) void*)(g),
      (__attribute__((address_space(3))) void*)(l),
      16, 0, 0);
}

// ---------------- prep: cast x to bf16 ----------------
__global__ __launch_bounds__(256) void k_cvt_x(const float* __restrict__ x,
                                               u16* __restrict__ xb) {
  int i = (blockIdx.x * 256 + threadIdx.x) * 4;
  float4 v = *(const float4*)&x[i];
  ushort4 o;
  o.x = f2b(v.x); o.y = f2b(v.y); o.z = f2b(v.z); o.w = f2b(v.w);
  *(ushort4*)&xb[i] = o;
}

// ---------------- prep: transpose weight (K x N f32) -> (N x K bf16) ----------------
__global__ __launch_bounds__(256) void k_transpose(const float* __restrict__ W,
                                                   u16* __restrict__ WT,
                                                   int K, int N) {
  __shared__ u16 t[32][33];
  int bx = blockIdx.x * 32, by = blockIdx.y * 32;
  int x = threadIdx.x & 31, y = threadIdx.x >> 5;  // y in 0..7
  for (int j = 0; j < 4; ++j) {
    int r = y + j * 8;
    t[r][x] = f2b(W[(size_t)(by + r) * N + bx + x]);
  }
  __syncthreads();
  for (int j = 0; j < 4; ++j) {
    int r = y + j * 8;
    WT[(size_t)(bx + r) * K + by + x] = t[x][r];  // WT[n][k] = W[k][n]
  }
}

// ---------------- GEMM: C[M,N] = A[M,K] * Bt[N,K], bf16 in ----------------
template <bool F32OUT>
__global__ __launch_bounds__(256) void k_gemm(const u16* __restrict__ A,
                                              const u16* __restrict__ Bt,
                                              void* __restrict__ Cout,
                                              int M, int N, int K) {
  __shared__ u16 As[2][128 * 64];
  __shared__ u16 Bs[2][128 * 64];
  const int tid = threadIdx.x;
  const int lane = tid & 63, wid = tid >> 6;
  const int l15 = lane & 15, lg = lane >> 4;
  const int bm = blockIdx.x * 128, bn = blockIdx.y * 128;
  const int wr = (wid >> 1) * 64, wc = (wid & 1) * 64;

  f4 acc[4][4] = {};

  const int srow = wid * 32 + (lane >> 3);
  const int scol = (lane & 7) * 8;
  const u16* gA = A  + (size_t)(bm + srow) * K + scol;
  const u16* gB = Bt + (size_t)(bn + srow) * K + scol;

  const int nk = K >> 6;

  {
    const u16* ga = gA; const u16* gb = gB;
    u16* la = &As[0][(wid * 32) * 64];
    u16* lb = &Bs[0][(wid * 32) * 64];
    #pragma unroll
    for (int c = 0; c < 4; ++c) {
      gload16(ga, la);
      gload16(gb, lb);
      ga += (size_t)8 * K; gb += (size_t)8 * K;
      la += 8 * 64;        lb += 8 * 64;
    }
  }
  __syncthreads();

  for (int t = 0; t < nk; ++t) {
    if (t + 1 < nk) {
      int kb = (t + 1) << 6;
      const u16* ga = gA + kb; const u16* gb = gB + kb;
      u16* la = &As[(t + 1) & 1][(wid * 32) * 64];
      u16* lb = &Bs[(t + 1) & 1][(wid * 32) * 64];
      #pragma unroll
      for (int c = 0; c < 4; ++c) {
        gload16(ga, la);
        gload16(gb, lb);
        ga += (size_t)8 * K; gb += (size_t)8 * K;
        la += 8 * 64;        lb += 8 * 64;
      }
    }
    const u16* as = &As[t & 1][0];
    const u16* bs = &Bs[t & 1][0];
    #pragma unroll
    for (int kk = 0; kk < 2; ++kk) {
      bh8 a[4], b[4];
      #pragma unroll
      for (int m = 0; m < 4; ++m)
        a[m] = *(const bh8*)&as[(wr + m * 16 + l15) * 64 + kk * 32 + lg * 8];
      #pragma unroll
      for (int n = 0; n < 4; ++n)
        b[n] = *(const bh8*)&bs[(wc + n * 16 + l15) * 64 + kk * 32 + lg * 8];
      #pragma unroll
      for (int m = 0; m < 4; ++m)
        #pragma unroll
        for (int n = 0; n < 4; ++n)
          acc[m][n] = __builtin_amdgcn_mfma_f32_16x16x32_bf16(a[m], b[n], acc[m][n], 0, 0, 0);
    }
    __syncthreads();
  }

  for (int m = 0; m < 4; ++m)
    for (int n = 0; n < 4; ++n)
      for (int r = 0; r < 4; ++r) {
        int row = bm + wr + m * 16 + lg * 4 + r;
        int col = bn + wc + n * 16 + l15;
        float v = acc[m][n][r];
        if constexpr (F32OUT) ((float*)Cout)[(size_t)row * N + col] = v;
        else                  ((u16*)Cout)[(size_t)row * N + col]  = f2b(v);
      }
}

// ---------------- RMSNorm + RoPE for Q,K ----------------
__global__ __launch_bounds__(256) void k_normrope(const u16* __restrict__ qkv,
                                                  const float* __restrict__ qw,
                                                  const float* __restrict__ kw,
                                                  const float* __restrict__ cosp,
                                                  const float* __restrict__ sinp,
                                                  u16* __restrict__ Q,
                                                  u16* __restrict__ K) {
  int gw = blockIdx.x * 4 + (threadIdx.x >> 6);   // one wave per (b,l,h)
  int lane = threadIdx.x & 63;
  int h = gw & 15;
  int bl = gw >> 4;             // b*2048 + l
  int l = bl & 2047;
  int b = bl >> 11;
  const u16* base = qkv + (size_t)bl * 3072 + h * 64;
  float qv = b2f(base[lane]);
  float kv = b2f(base[1024 + lane]);
  float qs = qv * qv, ks = kv * kv;
  for (int off = 1; off < 64; off <<= 1) {
    qs += __shfl_xor(qs, off, 64);
    ks += __shfl_xor(ks, off, 64);
  }
  float qr = rsqrtf(qs * (1.0f / 64.0f) + 1e-6f);
  float kr = rsqrtf(ks * (1.0f / 64.0f) + 1e-6f);
  float qn = qv * qr * qw[lane];
  float kn = kv * kr * kw[lane];
  int d2 = lane & 31;
  float c = cosp[l * 32 + d2], s = sinp[l * 32 + d2];
  float qp = __shfl_xor(qn, 32, 64);
  float kp = __shfl_xor(kn, 32, 64);
  float qo = (lane < 32) ? (qn * c - qp * s) : (qp * s + qn * c);
  float ko = (lane < 32) ? (kn * c - kp * s) : (kp * s + kn * c);
  size_t oi = (size_t)((b * 16 + h) * 2048 + l) * 64 + lane;
  Q[oi] = f2b(qo);
  K[oi] = f2b(ko);
}

// ---------------- V transpose: qkv V-slice -> Vt [B,H,D=64,L=2048] ----------------
__global__ __launch_bounds__(256) void k_vtrans(const u16* __restrict__ qkv,
                                                u16* __restrict__ Vt) {
  __shared__ u16 t[32][33];
  int bh = blockIdx.z; int b = bh >> 4, h = bh & 15;
  int lb = blockIdx.x * 32, db = blockIdx.y * 32;
  int x = threadIdx.x & 31, y = threadIdx.x >> 5;
  const u16* src = qkv + (size_t)b * 2048 * 3072 + 2048 + h * 64;
  for (int j = 0; j < 4; ++j) {
    int r = y + j * 8;
    t[r][x] = src[(size_t)(lb + r) * 3072 + db + x];
  }
  __syncthreads();
  u16* dst = Vt + (size_t)bh * 64 * 2048;
  for (int j = 0; j < 4; ++j) {
    int r = y + j * 8;
    dst[(size_t)(db + r) * 2048 + lb + x] = t[x][r];
  }
}

// ---------------- flash attention, causal; swapped-MFMA + split-K ----------------
// grid: (24, B*H). id<8: q-tile id, full key range. id>=8: q-tile 8+(id-8)/2,
// key-chunk (id-8)&1 of 2; partials (unnormalized O, m, l in log2 domain) -> ws.
__global__ __launch_bounds__(256, 3) void k_attn(const u16* __restrict__ Q,
                                                 const u16* __restrict__ K,
                                                 const u16* __restrict__ Vt,
                                                 u16* __restrict__ O,
                                                 float* __restrict__ Opart,
                                                 float2* __restrict__ Ml) {
  __shared__ u16 Ks[2][64 * 64];   // [k-local][d], XOR-swizzled chunks
  __shared__ u16 Vs[2][64 * 64];   // [d][k-local], XOR-swizzled chunks
  __shared__ u16 Pl[4][32][80];    // per-wave P [q-local][k-local]

  const float CSC = 0.125f * 1.44269504088896f;   // scale * log2(e)

  const int bh = blockIdx.y;
  const int b = bh >> 4, h = bh & 15;
  const int wid = threadIdx.x >> 6, lane = threadIdx.x & 63;
  const int l15 = lane & 15, lg = lane >> 4;

  const int id = blockIdx.x;
  int qt, t0, t1, half, nsplit;
  if (id < 8) { qt = id; half = 0; nsplit = 1; t0 = 0; t1 = 2 * qt + 2; }
  else {
    int p2 = id - 8;
    qt = 8 + (p2 >> 1); half = p2 & 1; nsplit = 2;
    int ht = qt + 1; t0 = half * ht; t1 = t0 + ht;
  }
  const int qb = qt * 128 + wid * 32;

  const u16* Qp = Q  + (size_t)bh * 2048 * 64;
  const u16* Kp = K  + (size_t)bh * 2048 * 64;
  const u16* Vp = Vt + (size_t)bh * 64 * 2048;

  const int sr0 = wid * 8 + (lane >> 3);
  const int sc  = lane & 7;

  bh8 aq[2][2];
  #pragma unroll
  for (int qi = 0; qi < 2; ++qi)
    #pragma unroll
    for (int hh = 0; hh < 2; ++hh)
      aq[qi][hh] = *(const bh8*)&Qp[(size_t)(qb + qi * 16 + l15) * 64 + hh * 32 + lg * 8];

  f4 acc[2][4] = {};
  float mrow[2] = {-1e30f, -1e30f};   // log2 domain
  float lrow[2] = {0.0f, 0.0f};

  const int tmax = (qb + 31) >> 6;   // last tile this wave needs

  // prologue: stage tile t0
  {
    int kb0 = t0 * 64;
    int r0 = sr0, r1 = 32 + sr0;
    gload16(Kp + (size_t)(kb0 + r0) * 64 + (size_t)((sc ^ (r0 & 7)) * 8), &Ks[t0 & 1][(wid * 8) * 64]);
    gload16(Kp + (size_t)(kb0 + r1) * 64 + (size_t)((sc ^ (r1 & 7)) * 8), &Ks[t0 & 1][(32 + wid * 8) * 64]);
    gload16(Vp + (size_t)r0 * 2048 + kb0 + (size_t)((sc ^ (r0 & 7)) * 8), &Vs[t0 & 1][(wid * 8) * 64]);
    gload16(Vp + (size_t)r1 * 2048 + kb0 + (size_t)((sc ^ (r1 & 7)) * 8), &Vs[t0 & 1][(32 + wid * 8) * 64]);
  }
  __syncthreads();

  for (int t = t0; t < t1; ++t) {
    if (t + 1 < t1) {
      int kb = (t + 1) * 64;
      int nb = (t + 1) & 1;
      int r0 = sr0, r1 = 32 + sr0;
      gload16(Kp + (size_t)(kb + r0) * 64 + (size_t)((sc ^ (r0 & 7)) * 8), &Ks[nb][(wid * 8) * 64]);
      gload16(Kp + (size_t)(kb + r1) * 64 + (size_t)((sc ^ (r1 & 7)) * 8), &Ks[nb][(32 + wid * 8) * 64]);
      gload16(Vp + (size_t)r0 * 2048 + kb + (size_t)((sc ^ (r0 & 7)) * 8), &Vs[nb][(wid * 8) * 64]);
      gload16(Vp + (size_t)r1 * 2048 + kb + (size_t)((sc ^ (r1 & 7)) * 8), &Vs[nb][(32 + wid * 8) * 64]);
    }
    if (t <= tmax) {
      const int kb = t * 64;
      const u16* ks = &Ks[t & 1][0];
      const u16* vs = &Vs[t & 1][0];

      // ---- QK^T (swapped): D col=q ----
      f4 s[4][2] = {};
      __builtin_amdgcn_s_setprio(1);
      #pragma unroll
      for (int kq = 0; kq < 4; ++kq) {
        int row = kq * 16 + l15;
        int cs = row & 7;
        bh8 ka0 = *(const bh8*)&ks[row * 64 + ((0 + lg) ^ cs) * 8];
        bh8 ka1 = *(const bh8*)&ks[row * 64 + ((4 + lg) ^ cs) * 8];
        #pragma unroll
        for (int qi = 0; qi < 2; ++qi) {
          s[kq][qi] = __builtin_amdgcn_mfma_f32_16x16x32_bf16(ka0, aq[qi][0], s[kq][qi], 0, 0, 0);
          s[kq][qi] = __builtin_amdgcn_mfma_f32_16x16x32_bf16(ka1, aq[qi][1], s[kq][qi], 0, 0, 0);
        }
      }
      __builtin_amdgcn_s_setprio(0);

      // ---- online softmax (log2 domain), defer-max THR=8 ----
      float p[4][2][4];
      #pragma unroll
      for (int qi = 0; qi < 2; ++qi) {
        int q = qb + qi * 16 + l15;
        float mx = -1e30f;
        #pragma unroll
        for (int kq = 0; kq < 4; ++kq)
          #pragma unroll
          for (int r = 0; r < 4; ++r) {
            int k = kb + kq * 16 + lg * 4 + r;
            float v = (k <= q) ? s[kq][qi][r] * CSC : -1e30f;
            p[kq][qi][r] = v;
            mx = fmaxf(mx, v);
          }
        mx = fmaxf(mx, __shfl_xor(mx, 16, 64));
        mx = fmaxf(mx, __shfl_xor(mx, 32, 64));
        if (__any(mx > mrow[qi] + 8.0f)) {
          float mnew = fmaxf(mrow[qi], mx);
          float fac = exp2f(mrow[qi] - mnew);
          mrow[qi] = mnew;
          lrow[qi] *= fac;
          #pragma unroll
          for (int n = 0; n < 4; ++n)
            #pragma unroll
            for (int r = 0; r < 4; ++r) acc[qi][n][r] *= fac;
        }
        float ps = 0.0f;
        #pragma unroll
        for (int kq = 0; kq < 4; ++kq)
          #pragma unroll
          for (int r = 0; r < 4; ++r) {
            float e = exp2f(p[kq][qi][r] - mrow[qi]);
            p[kq][qi][r] = e;
            ps += e;
          }
        ps += __shfl_xor(ps, 16, 64);
        ps += __shfl_xor(ps, 32, 64);
        lrow[qi] += ps;
      }

      // ---- P -> per-wave LDS [q][k] ----
      #pragma unroll
      for (int qi = 0; qi < 2; ++qi)
        #pragma unroll
        for (int kq = 0; kq < 4; ++kq) {
          ushort4 w4;
          w4.x = f2b(p[kq][qi][0]); w4.y = f2b(p[kq][qi][1]);
          w4.z = f2b(p[kq][qi][2]); w4.w = f2b(p[kq][qi][3]);
          *(ushort4*)&Pl[wid][qi * 16 + l15][kq * 16 + lg * 4] = w4;
        }
      asm volatile("s_waitcnt lgkmcnt(0)" ::: "memory");
      __builtin_amdgcn_sched_barrier(0);

      // ---- PV (double-swapped): D col=q ----
      __builtin_amdgcn_s_setprio(1);
      #pragma unroll
      for (int g = 0; g < 2; ++g) {
        bh8 pb0 = *(const bh8*)&Pl[wid][l15][g * 32 + lg * 8];
        bh8 pb1 = *(const bh8*)&Pl[wid][16 + l15][g * 32 + lg * 8];
        #pragma unroll
        for (int n = 0; n < 4; ++n) {
          int row = n * 16 + l15;
          bh8 va = *(const bh8*)&vs[row * 64 + (((g * 4 + lg) ^ (row & 7)) * 8)];
          acc[0][n] = __builtin_amdgcn_mfma_f32_16x16x32_bf16(va, pb0, acc[0][n], 0, 0, 0);
          acc[1][n] = __builtin_amdgcn_mfma_f32_16x16x32_bf16(va, pb1, acc[1][n], 0, 0, 0);
        }
      }
      __builtin_amdgcn_s_setprio(0);
    }
    __syncthreads();
  }

  if (nsplit == 1) {
    #pragma unroll
    for (int qi = 0; qi < 2; ++qi) {
      float inv = 1.0f / lrow[qi];
      int q = qb + qi * 16 + l15;
      #pragma unroll
      for (int n = 0; n < 4; ++n) {
        ushort4 w4;
        w4.x = f2b(acc[qi][n][0] * inv);
        w4.y = f2b(acc[qi][n][1] * inv);
        w4.z = f2b(acc[qi][n][2] * inv);
        w4.w = f2b(acc[qi][n][3] * inv);
        *(ushort4*)&O[((size_t)b * 2048 + q) * 1024 + h * 64 + n * 16 + lg * 4] = w4;
      }
    }
  } else {
    int slot = ((bh * 8) + (qt - 8)) * 2 + half;
    float* op = Opart + (size_t)slot * 128 * 64;
    #pragma unroll
    for (int qi = 0; qi < 2; ++qi) {
      int rloc = wid * 32 + qi * 16 + l15;
      #pragma unroll
      for (int n = 0; n < 4; ++n) {
        float4 v4 = make_float4(acc[qi][n][0], acc[qi][n][1], acc[qi][n][2], acc[qi][n][3]);
        *(float4*)&op[(size_t)rloc * 64 + n * 16 + lg * 4] = v4;
      }
      if (lg == 0) Ml[slot * 128 + rloc] = make_float2(mrow[qi], lrow[qi]);
    }
  }
}

// ---------------- combine split-K partials ----------------
__global__ __launch_bounds__(256) void k_comb(const float* __restrict__ Opart,
                                              const float2* __restrict__ Ml,
                                              u16* __restrict__ O) {
  int qt8 = blockIdx.x, bh = blockIdx.y;
  int b = bh >> 4, h = bh & 15, qt = 8 + qt8;
  int tid = threadIdx.x;
  int row = tid >> 1, dbase = (tid & 1) * 32;
  int slot = (bh * 8 + qt8) * 2;
  float2 a = Ml[slot * 128 + row];
  float2 c = Ml[(slot + 1) * 128 + row];
  float M = fmaxf(a.x, c.x);
  float w1 = exp2f(a.x - M), w2 = exp2f(c.x - M);
  float inv = 1.0f / (w1 * a.y + w2 * c.y);
  const float* o1 = Opart + (size_t)slot * 8192 + (size_t)row * 64 + dbase;
  const float* o2 = o1 + 8192;
  u16* dst = O + ((size_t)b * 2048 + qt * 128 + row) * 1024 + h * 64 + dbase;
  #pragma unroll
  for (int j = 0; j < 32; j += 4) {
    float4 v1 = *(const float4*)&o1[j];
    float4 v2 = *(const float4*)&o2[j];
    ushort4 w4;
    w4.x = f2b((v1.x * w1 + v2.x * w2) * inv);
    w4.y = f2b((v1.y * w1 + v2.y * w2) * inv);
    w4.z = f2b((v1.z * w1 + v2.z * w2) * inv);
    w4.w = f2b((v1.w * w1 + v2.w * w2) * inv);
    *(ushort4*)&dst[j] = w4;
  }
}

extern "C" void kernel_launch(void* const* d_in, const int* in_sizes, int n_in,
                              void* d_out, int out_size, void* d_ws, size_t ws_size,
                              hipStream_t stream) {
  (void)in_sizes; (void)n_in; (void)out_size; (void)ws_size;
  const float* x    = (const float*)d_in[0];
  const float* Wqkv = (const float*)d_in[1];
  const float* Wo   = (const float*)d_in[2];
  const float* qw   = (const float*)d_in[3];
  const float* kw   = (const float*)d_in[4];
  const float* cosp = (const float*)d_in[5];
  const float* sinp = (const float*)d_in[6];
  float* out = (float*)d_out;

  char* ws = (char*)d_ws;
  u16* xb    = (u16*)(ws);                 //  8,388,608 B  x bf16 [4096][1024]
  u16* wqkvT = (u16*)(ws + 8388608);       //  6,291,456 B  Wqkv^T bf16
  u16* woT   = (u16*)(ws + 14680064);      //  2,097,152 B  Wo^T bf16
  u16* qkv   = (u16*)(ws + 16777216);      // 25,165,824 B  qkv bf16 [4096][3072]
  u16* Qb    = (u16*)(ws + 41943040);      //  8,388,608 B  [B,H,L,D]
  u16* Kb    = (u16*)(ws + 50331648);      //  8,388,608 B
  u16* Vtb   = (u16*)(ws + 58720256);      //  8,388,608 B  [B,H,D,L]
  u16* AO    = (u16*)(ws + 67108864);      //  8,388,608 B  attn_out bf16
  // split-K partials overlay the qkv region (qkv is dead once attn starts)
  float*  Opart = (float*)(ws + 16777216);   // 16,777,216 B (512 slots * 128*64 f32)
  float2* Mlb   = (float2*)(ws + 33554432);  //    524,288 B (512 slots * 128 float2)

  k_cvt_x<<<4096, 256, 0, stream>>>(x, xb);
  k_transpose<<<dim3(96, 32), 256, 0, stream>>>(Wqkv, wqkvT, 1024, 3072);
  k_transpose<<<dim3(32, 32), 256, 0, stream>>>(Wo, woT, 1024, 1024);
  k_gemm<false><<<dim3(32, 24), 256, 0, stream>>>(xb, wqkvT, qkv, 4096, 3072, 1024);
  k_normrope<<<16384, 256, 0, stream>>>(qkv, qw, kw, cosp, sinp, Qb, Kb);
  k_vtrans<<<dim3(64, 2, 32), 256, 0, stream>>>(qkv, Vtb);
  k_attn<<<dim3(24, 32), 256, 0, stream>>>(Qb, Kb, Vtb, AO, Opart, Mlb);
  k_comb<<<dim3(8, 32), 256, 0, stream>>>(Opart, Mlb, AO);
  k_gemm<true><<<dim3(32, 8), 256, 0, stream>>>(AO, woT, out, 4096, 1024, 1024);
}

// Round 6
// 163.270 us; speedup vs baseline: 4.2598x; 1.0592x over previous
//
#include <hip/hip_runtime.h>
#include <hip/hip_bf16.h>

typedef __attribute__((ext_vector_type(8))) short bh8;   // 8 bf16 in 4 VGPRs
typedef __attribute__((ext_vector_type(4))) float f4;    // MFMA accumulator

typedef unsigned short u16;
typedef unsigned int u32;

__device__ inline u16 f2b(float f) {
  __hip_bfloat16 h = __float2bfloat16(f);   // compiler packs pairs -> v_cvt_pk_bf16_f32
  union { __hip_bfloat16 h; u16 u; } v; v.h = h; return v.u;
}
__device__ inline float b2f(u16 b) {
  union { u32 u; float f; } v; v.u = ((u32)b) << 16;
  return v.f;
}

// async global->LDS, 16B per lane; LDS dest is wave-uniform base + lane*16
__device__ __forceinline__ void gload16(const u16* g, u16* l) {
  __builtin_amdgcn_global_load_lds(
      (__attribute__((address_space(1))) void*)(g),
      (__attribute__((address_space(3))) void*)(l),
      16, 0, 0);
}

// ---------------- prep: cast x to bf16 ----------------
__global__ __launch_bounds__(256) void k_cvt_x(const float* __restrict__ x,
                                               u16* __restrict__ xb) {
  int i = (blockIdx.x * 256 + threadIdx.x) * 4;
  float4 v = *(const float4*)&x[i];
  ushort4 o;
  o.x = f2b(v.x); o.y = f2b(v.y); o.z = f2b(v.z); o.w = f2b(v.w);
  *(ushort4*)&xb[i] = o;
}

// ---------------- prep: transpose weight (K x N f32) -> (N x K bf16) ----------------
__global__ __launch_bounds__(256) void k_transpose(const float* __restrict__ W,
                                                   u16* __restrict__ WT,
                                                   int K, int N) {
  __shared__ u16 t[32][33];
  int bx = blockIdx.x * 32, by = blockIdx.y * 32;
  int x = threadIdx.x & 31, y = threadIdx.x >> 5;  // y in 0..7
  for (int j = 0; j < 4; ++j) {
    int r = y + j * 8;
    t[r][x] = f2b(W[(size_t)(by + r) * N + bx + x]);
  }
  __syncthreads();
  for (int j = 0; j < 4; ++j) {
    int r = y + j * 8;
    WT[(size_t)(bx + r) * K + by + x] = t[x][r];  // WT[n][k] = W[k][n]
  }
}

// ---------------- GEMM: C[M,N] = A[M,K] * Bt[N,K], bf16 in ----------------
template <bool F32OUT>
__global__ __launch_bounds__(256) void k_gemm(const u16* __restrict__ A,
                                              const u16* __restrict__ Bt,
                                              void* __restrict__ Cout,
                                              int M, int N, int K) {
  __shared__ u16 As[2][128 * 64];
  __shared__ u16 Bs[2][128 * 64];
  const int tid = threadIdx.x;
  const int lane = tid & 63, wid = tid >> 6;
  const int l15 = lane & 15, lg = lane >> 4;
  const int bm = blockIdx.x * 128, bn = blockIdx.y * 128;
  const int wr = (wid >> 1) * 64, wc = (wid & 1) * 64;

  f4 acc[4][4] = {};

  const int srow = wid * 32 + (lane >> 3);
  const int scol = (lane & 7) * 8;
  const u16* gA = A  + (size_t)(bm + srow) * K + scol;
  const u16* gB = Bt + (size_t)(bn + srow) * K + scol;

  const int nk = K >> 6;

  {
    const u16* ga = gA; const u16* gb = gB;
    u16* la = &As[0][(wid * 32) * 64];
    u16* lb = &Bs[0][(wid * 32) * 64];
    #pragma unroll
    for (int c = 0; c < 4; ++c) {
      gload16(ga, la);
      gload16(gb, lb);
      ga += (size_t)8 * K; gb += (size_t)8 * K;
      la += 8 * 64;        lb += 8 * 64;
    }
  }
  __syncthreads();

  for (int t = 0; t < nk; ++t) {
    if (t + 1 < nk) {
      int kb = (t + 1) << 6;
      const u16* ga = gA + kb; const u16* gb = gB + kb;
      u16* la = &As[(t + 1) & 1][(wid * 32) * 64];
      u16* lb = &Bs[(t + 1) & 1][(wid * 32) * 64];
      #pragma unroll
      for (int c = 0; c < 4; ++c) {
        gload16(ga, la);
        gload16(gb, lb);
        ga += (size_t)8 * K; gb += (size_t)8 * K;
        la += 8 * 64;        lb += 8 * 64;
      }
    }
    const u16* as = &As[t & 1][0];
    const u16* bs = &Bs[t & 1][0];
    #pragma unroll
    for (int kk = 0; kk < 2; ++kk) {
      bh8 a[4], b[4];
      #pragma unroll
      for (int m = 0; m < 4; ++m)
        a[m] = *(const bh8*)&as[(wr + m * 16 + l15) * 64 + kk * 32 + lg * 8];
      #pragma unroll
      for (int n = 0; n < 4; ++n)
        b[n] = *(const bh8*)&bs[(wc + n * 16 + l15) * 64 + kk * 32 + lg * 8];
      #pragma unroll
      for (int m = 0; m < 4; ++m)
        #pragma unroll
        for (int n = 0; n < 4; ++n)
          acc[m][n] = __builtin_amdgcn_mfma_f32_16x16x32_bf16(a[m], b[n], acc[m][n], 0, 0, 0);
    }
    __syncthreads();
  }

  for (int m = 0; m < 4; ++m)
    for (int n = 0; n < 4; ++n)
      for (int r = 0; r < 4; ++r) {
        int row = bm + wr + m * 16 + lg * 4 + r;
        int col = bn + wc + n * 16 + l15;
        float v = acc[m][n][r];
        if constexpr (F32OUT) ((float*)Cout)[(size_t)row * N + col] = v;
        else                  ((u16*)Cout)[(size_t)row * N + col]  = f2b(v);
      }
}

// ---------------- RMSNorm + RoPE for Q,K; Q pre-scaled by 0.125*log2(e) ----------------
__global__ __launch_bounds__(256) void k_normrope(const u16* __restrict__ qkv,
                                                  const float* __restrict__ qw,
                                                  const float* __restrict__ kw,
                                                  const float* __restrict__ cosp,
                                                  const float* __restrict__ sinp,
                                                  u16* __restrict__ Q,
                                                  u16* __restrict__ K) {
  const float CSC = 0.125f * 1.44269504088896f;
  int gw = blockIdx.x * 4 + (threadIdx.x >> 6);   // one wave per (b,l,h)
  int lane = threadIdx.x & 63;
  int h = gw & 15;
  int bl = gw >> 4;             // b*2048 + l
  int l = bl & 2047;
  int b = bl >> 11;
  const u16* base = qkv + (size_t)bl * 3072 + h * 64;
  float qv = b2f(base[lane]);
  float kv = b2f(base[1024 + lane]);
  float qs = qv * qv, ks = kv * kv;
  for (int off = 1; off < 64; off <<= 1) {
    qs += __shfl_xor(qs, off, 64);
    ks += __shfl_xor(ks, off, 64);
  }
  float qr = rsqrtf(qs * (1.0f / 64.0f) + 1e-6f);
  float kr = rsqrtf(ks * (1.0f / 64.0f) + 1e-6f);
  float qn = qv * qr * qw[lane];
  float kn = kv * kr * kw[lane];
  int d2 = lane & 31;
  float c = cosp[l * 32 + d2], s = sinp[l * 32 + d2];
  float qp = __shfl_xor(qn, 32, 64);
  float kp = __shfl_xor(kn, 32, 64);
  float qo = (lane < 32) ? (qn * c - qp * s) : (qp * s + qn * c);
  float ko = (lane < 32) ? (kn * c - kp * s) : (kp * s + kn * c);
  size_t oi = (size_t)((b * 16 + h) * 2048 + l) * 64 + lane;
  Q[oi] = f2b(qo * CSC);
  K[oi] = f2b(ko);
}

// ---------------- V transpose: qkv V-slice -> Vt [B,H,D=64,L=2048] ----------------
__global__ __launch_bounds__(256) void k_vtrans(const u16* __restrict__ qkv,
                                                u16* __restrict__ Vt) {
  __shared__ u16 t[32][33];
  int bh = blockIdx.z; int b = bh >> 4, h = bh & 15;
  int lb = blockIdx.x * 32, db = blockIdx.y * 32;
  int x = threadIdx.x & 31, y = threadIdx.x >> 5;
  const u16* src = qkv + (size_t)b * 2048 * 3072 + 2048 + h * 64;
  for (int j = 0; j < 4; ++j) {
    int r = y + j * 8;
    t[r][x] = src[(size_t)(lb + r) * 3072 + db + x];
  }
  __syncthreads();
  u16* dst = Vt + (size_t)bh * 64 * 2048;
  for (int j = 0; j < 4; ++j) {
    int r = y + j * 8;
    dst[(size_t)(db + r) * 2048 + lb + x] = t[x][r];
  }
}

// ---------------- flash attention, causal; swapped-MFMA, balanced split-K ----------------
// grid: (33, B*H). id 0..4: qt=id full. id 5..14: qt=5+(id-5)/2 2-way.
// id 15..32: qt=10+(id-15)/3 3-way. Partials (bf16 O, f32 m/l) -> ws. Diag tile == tmax.
__global__ __launch_bounds__(256, 3) void k_attn(const u16* __restrict__ Q,
                                                 const u16* __restrict__ K,
                                                 const u16* __restrict__ Vt,
                                                 u16* __restrict__ O,
                                                 u16* __restrict__ Opart,
                                                 float2* __restrict__ Ml) {
  __shared__ u16 Ks[2][64 * 64];   // [k-local][d], XOR-swizzled chunks
  __shared__ u16 Vs[2][64 * 64];   // [d][k-local], XOR-swizzled chunks
  __shared__ u16 Pl[4][32][64];    // per-wave P, XOR-swizzled 16B chunks

  const int bh = blockIdx.y;
  const int b = bh >> 4, h = bh & 15;
  const int wid = threadIdx.x >> 6, lane = threadIdx.x & 63;
  const int l15 = lane & 15, lg = lane >> 4;

  const int id = 32 - (int)blockIdx.x;    // longest work dispatched first
  int qt, t0, t1, slot;
  if (id < 5) { qt = id; t0 = 0; t1 = 2 * qt + 2; slot = -1; }
  else if (id < 15) {
    int p2 = id - 5; qt = 5 + (p2 >> 1); int half = p2 & 1;
    int nt = qt + 1; t0 = half * nt; t1 = t0 + nt;
    slot = bh * 28 + (qt - 5) * 2 + half;
  } else {
    int p3 = id - 15; qt = 10 + p3 / 3; int part = p3 % 3;
    int T = 2 * qt + 2; t0 = (part * T) / 3; t1 = ((part + 1) * T) / 3;
    slot = bh * 28 + 10 + (qt - 10) * 3 + part;
  }
  const int qb = qt * 128 + wid * 32;

  const u16* Qp = Q  + (size_t)bh * 2048 * 64;
  const u16* Kp = K  + (size_t)bh * 2048 * 64;
  const u16* Vp = Vt + (size_t)bh * 64 * 2048;

  const int sr0 = wid * 8 + (lane >> 3);
  const int sc  = lane & 7;

  bh8 aq[2][2];
  #pragma unroll
  for (int qi = 0; qi < 2; ++qi)
    #pragma unroll
    for (int hh = 0; hh < 2; ++hh)
      aq[qi][hh] = *(const bh8*)&Qp[(size_t)(qb + qi * 16 + l15) * 64 + hh * 32 + lg * 8];

  bh8 ones;
  #pragma unroll
  for (int j = 0; j < 8; ++j) ones[j] = (short)0x3F80;

  f4 acc[2][4] = {};
  float mrow[2] = {-1e30f, -1e30f};   // log2 domain
  float lrow[2] = {0.0f, 0.0f};

  const int tmax = (qb + 31) >> 6;   // last (diagonal) tile this wave needs

  // prologue: stage tile t0
  {
    int kb0 = t0 * 64;
    int r0 = sr0, r1 = 32 + sr0;
    gload16(Kp + (size_t)(kb0 + r0) * 64 + (size_t)((sc ^ (r0 & 7)) * 8), &Ks[t0 & 1][(wid * 8) * 64]);
    gload16(Kp + (size_t)(kb0 + r1) * 64 + (size_t)((sc ^ (r1 & 7)) * 8), &Ks[t0 & 1][(32 + wid * 8) * 64]);
    gload16(Vp + (size_t)r0 * 2048 + kb0 + (size_t)((sc ^ (r0 & 7)) * 8), &Vs[t0 & 1][(wid * 8) * 64]);
    gload16(Vp + (size_t)r1 * 2048 + kb0 + (size_t)((sc ^ (r1 & 7)) * 8), &Vs[t0 & 1][(32 + wid * 8) * 64]);
  }
  __syncthreads();

  for (int t = t0; t < t1; ++t) {
    if (t + 1 < t1) {
      int kb = (t + 1) * 64;
      int nb = (t + 1) & 1;
      int r0 = sr0, r1 = 32 + sr0;
      gload16(Kp + (size_t)(kb + r0) * 64 + (size_t)((sc ^ (r0 & 7)) * 8), &Ks[nb][(wid * 8) * 64]);
      gload16(Kp + (size_t)(kb + r1) * 64 + (size_t)((sc ^ (r1 & 7)) * 8), &Ks[nb][(32 + wid * 8) * 64]);
      gload16(Vp + (size_t)r0 * 2048 + kb + (size_t)((sc ^ (r0 & 7)) * 8), &Vs[nb][(wid * 8) * 64]);
      gload16(Vp + (size_t)r1 * 2048 + kb + (size_t)((sc ^ (r1 & 7)) * 8), &Vs[nb][(32 + wid * 8) * 64]);
    }
    if (t <= tmax) {
      const int kb = t * 64;
      const bool masked = (t == tmax);
      const u16* ks = &Ks[t & 1][0];
      const u16* vs = &Vs[t & 1][0];

      // ---- QK^T (swapped): D col=q; Q pre-scaled ----
      f4 s[4][2] = {};
      __builtin_amdgcn_s_setprio(1);
      #pragma unroll
      for (int kq = 0; kq < 4; ++kq) {
        int row = kq * 16 + l15;
        int cs = row & 7;
        bh8 ka0 = *(const bh8*)&ks[row * 64 + ((0 + lg) ^ cs) * 8];
        bh8 ka1 = *(const bh8*)&ks[row * 64 + ((4 + lg) ^ cs) * 8];
        #pragma unroll
        for (int qi = 0; qi < 2; ++qi) {
          s[kq][qi] = __builtin_amdgcn_mfma_f32_16x16x32_bf16(ka0, aq[qi][0], s[kq][qi], 0, 0, 0);
          s[kq][qi] = __builtin_amdgcn_mfma_f32_16x16x32_bf16(ka1, aq[qi][1], s[kq][qi], 0, 0, 0);
        }
      }
      __builtin_amdgcn_s_setprio(0);

      // ---- online softmax (log2 domain), defer-max THR=8, mask only diag ----
      #pragma unroll
      for (int qi = 0; qi < 2; ++qi) {
        if (masked) {
          int q = qb + qi * 16 + l15;
          #pragma unroll
          for (int kq = 0; kq < 4; ++kq)
            #pragma unroll
            for (int r = 0; r < 4; ++r)
              if (kb + kq * 16 + lg * 4 + r > q) s[kq][qi][r] = -1e30f;
        }
        float mx = s[0][qi][0];
        #pragma unroll
        for (int kq = 0; kq < 4; ++kq)
          #pragma unroll
          for (int r = 0; r < 4; ++r)
            if (kq + r) mx = fmaxf(mx, s[kq][qi][r]);
        mx = fmaxf(mx, __shfl_xor(mx, 16, 64));
        mx = fmaxf(mx, __shfl_xor(mx, 32, 64));
        if (__any(mx > mrow[qi] + 8.0f)) {
          float mnew = fmaxf(mrow[qi], mx);
          float fac = exp2f(mrow[qi] - mnew);
          mrow[qi] = mnew;
          lrow[qi] *= fac;
          #pragma unroll
          for (int n = 0; n < 4; ++n)
            #pragma unroll
            for (int r = 0; r < 4; ++r) acc[qi][n][r] *= fac;
        }
        #pragma unroll
        for (int kq = 0; kq < 4; ++kq)
          #pragma unroll
          for (int r = 0; r < 4; ++r)
            s[kq][qi][r] = exp2f(s[kq][qi][r] - mrow[qi]);
      }

      // ---- P -> per-wave LDS (XOR-swizzled 16B chunks) ----
      char* plb = (char*)&Pl[wid][0][0];
      #pragma unroll
      for (int qi = 0; qi < 2; ++qi) {
        int row = qi * 16 + l15;
        #pragma unroll
        for (int kq = 0; kq < 4; ++kq) {
          ushort4 w4;
          w4.x = f2b(s[kq][qi][0]); w4.y = f2b(s[kq][qi][1]);
          w4.z = f2b(s[kq][qi][2]); w4.w = f2b(s[kq][qi][3]);
          int ch = (kq * 2 + (lg >> 1)) ^ (row & 7);
          *(ushort4*)(plb + row * 128 + ch * 16 + (lg & 1) * 8) = w4;
        }
      }
      asm volatile("s_waitcnt lgkmcnt(0)" ::: "memory");
      __builtin_amdgcn_sched_barrier(0);

      // ---- PV (double-swapped) + row-sum via ones-MFMA ----
      f4 sum0 = {}, sum1 = {};
      __builtin_amdgcn_s_setprio(1);
      #pragma unroll
      for (int g = 0; g < 2; ++g) {
        bh8 pb0 = *(const bh8*)(plb + l15 * 128 + (((g * 4 + lg) ^ (l15 & 7)) * 16));
        bh8 pb1 = *(const bh8*)(plb + (16 + l15) * 128 + (((g * 4 + lg) ^ (l15 & 7)) * 16));
        #pragma unroll
        for (int n = 0; n < 4; ++n) {
          int row = n * 16 + l15;
          bh8 va = *(const bh8*)&vs[row * 64 + (((g * 4 + lg) ^ (row & 7)) * 8)];
          acc[0][n] = __builtin_amdgcn_mfma_f32_16x16x32_bf16(va, pb0, acc[0][n], 0, 0, 0);
          acc[1][n] = __builtin_amdgcn_mfma_f32_16x16x32_bf16(va, pb1, acc[1][n], 0, 0, 0);
        }
        sum0 = __builtin_amdgcn_mfma_f32_16x16x32_bf16(ones, pb0, sum0, 0, 0, 0);
        sum1 = __builtin_amdgcn_mfma_f32_16x16x32_bf16(ones, pb1, sum1, 0, 0, 0);
      }
      __builtin_amdgcn_s_setprio(0);
      lrow[0] += sum0[0];
      lrow[1] += sum1[0];
    }
    __syncthreads();
  }

  if (slot < 0) {
    #pragma unroll
    for (int qi = 0; qi < 2; ++qi) {
      float inv = 1.0f / lrow[qi];
      int q = qb + qi * 16 + l15;
      #pragma unroll
      for (int n = 0; n < 4; ++n) {
        ushort4 w4;
        w4.x = f2b(acc[qi][n][0] * inv);
        w4.y = f2b(acc[qi][n][1] * inv);
        w4.z = f2b(acc[qi][n][2] * inv);
        w4.w = f2b(acc[qi][n][3] * inv);
        *(ushort4*)&O[((size_t)b * 2048 + q) * 1024 + h * 64 + n * 16 + lg * 4] = w4;
      }
    }
  } else {
    u16* op = Opart + (size_t)slot * 8192;
    #pragma unroll
    for (int qi = 0; qi < 2; ++qi) {
      int rloc = wid * 32 + qi * 16 + l15;
      #pragma unroll
      for (int n = 0; n < 4; ++n) {
        ushort4 w4;
        w4.x = f2b(acc[qi][n][0]); w4.y = f2b(acc[qi][n][1]);
        w4.z = f2b(acc[qi][n][2]); w4.w = f2b(acc[qi][n][3]);
        *(ushort4*)&op[(size_t)rloc * 64 + n * 16 + lg * 4] = w4;
      }
      if (lg == 0) Ml[slot * 128 + rloc] = make_float2(mrow[qi], lrow[qi]);
    }
  }
}

// ---------------- combine split-K partials (2- or 3-way) ----------------
__global__ __launch_bounds__(256) void k_comb(const u16* __restrict__ Opart,
                                              const float2* __restrict__ Ml,
                                              u16* __restrict__ O) {
  int qx = blockIdx.x;              // 0..10 -> qt = 5+qx
  int bh = blockIdx.y;
  int b = bh >> 4, h = bh & 15;
  int qt = 5 + qx;
  int ways = (qt < 10) ? 2 : 3;
  int base = bh * 28 + ((qt < 10) ? (qt - 5) * 2 : 10 + (qt - 10) * 3);
  int row = threadIdx.x >> 1;
  int db  = (threadIdx.x & 1) * 32;

  float2 ml[3]; float wgt[3];
  float M = -1e30f;
  #pragma unroll
  for (int w = 0; w < 3; ++w)
    if (w < ways) { ml[w] = Ml[(base + w) * 128 + row]; M = fmaxf(M, ml[w].x); }
  float l = 0.0f;
  #pragma unroll
  for (int w = 0; w < 3; ++w)
    if (w < ways) { wgt[w] = exp2f(ml[w].x - M); l += wgt[w] * ml[w].y; }
  float inv = 1.0f / l;

  u16* dst = O + ((size_t)b * 2048 + qt * 128 + row) * 1024 + h * 64 + db;
  #pragma unroll
  for (int j = 0; j < 32; j += 8) {
    float a[8] = {};
    #pragma unroll
    for (int w = 0; w < 3; ++w)
      if (w < ways) {
        bh8 v = *(const bh8*)&Opart[(size_t)(base + w) * 8192 + (size_t)row * 64 + db + j];
        #pragma unroll
        for (int e = 0; e < 8; ++e) a[e] += wgt[w] * b2f((u16)v[e]);
      }
    bh8 o;
    #pragma unroll
    for (int e = 0; e < 8; ++e) o[e] = (short)f2b(a[e] * inv);
    *(bh8*)&dst[j] = o;
  }
}

extern "C" void kernel_launch(void* const* d_in, const int* in_sizes, int n_in,
                              void* d_out, int out_size, void* d_ws, size_t ws_size,
                              hipStream_t stream) {
  (void)in_sizes; (void)n_in; (void)out_size; (void)ws_size;
  const float* x    = (const float*)d_in[0];
  const float* Wqkv = (const float*)d_in[1];
  const float* Wo   = (const float*)d_in[2];
  const float* qw   = (const float*)d_in[3];
  const float* kw   = (const float*)d_in[4];
  const float* cosp = (const float*)d_in[5];
  const float* sinp = (const float*)d_in[6];
  float* out = (float*)d_out;

  char* ws = (char*)d_ws;
  u16* xb    = (u16*)(ws);                 //  8,388,608 B  x bf16 [4096][1024]
  u16* wqkvT = (u16*)(ws + 8388608);       //  6,291,456 B  Wqkv^T bf16
  u16* woT   = (u16*)(ws + 14680064);      //  2,097,152 B  Wo^T bf16
  u16* qkv   = (u16*)(ws + 16777216);      // 25,165,824 B  qkv bf16 [4096][3072]
  u16* Qb    = (u16*)(ws + 41943040);      //  8,388,608 B  [B,H,L,D]
  u16* Kb    = (u16*)(ws + 50331648);      //  8,388,608 B
  u16* Vtb   = (u16*)(ws + 58720256);      //  8,388,608 B  [B,H,D,L]
  u16* AO    = (u16*)(ws + 67108864);      //  8,388,608 B  attn_out bf16
  // split-K partials overlay the dead qkv region
  u16*    Opart = (u16*)(ws + 16777216);     // 896 slots * 128*64 bf16 = 14,680,064 B
  float2* Mlb   = (float2*)(ws + 31457280);  // 896 slots * 128 float2  =    917,504 B

  k_cvt_x<<<4096, 256, 0, stream>>>(x, xb);
  k_transpose<<<dim3(96, 32), 256, 0, stream>>>(Wqkv, wqkvT, 1024, 3072);
  k_transpose<<<dim3(32, 32), 256, 0, stream>>>(Wo, woT, 1024, 1024);
  k_gemm<false><<<dim3(32, 24), 256, 0, stream>>>(xb, wqkvT, qkv, 4096, 3072, 1024);
  k_normrope<<<16384, 256, 0, stream>>>(qkv, qw, kw, cosp, sinp, Qb, Kb);
  k_vtrans<<<dim3(64, 2, 32), 256, 0, stream>>>(qkv, Vtb);
  k_attn<<<dim3(33, 32), 256, 0, stream>>>(Qb, Kb, Vtb, AO, Opart, Mlb);
  k_comb<<<dim3(11, 32), 256, 0, stream>>>(Opart, Mlb, AO);
  k_gemm<true><<<dim3(32, 8), 256, 0, stream>>>(AO, woT, out, 4096, 1024, 1024);
}

// Round 7
// 154.049 us; speedup vs baseline: 4.5148x; 1.0599x over previous
//
#include <hip/hip_runtime.h>
#include <hip/hip_bf16.h>

typedef __attribute__((ext_vector_type(8))) short bh8;   // 8 bf16 in 4 VGPRs
typedef __attribute__((ext_vector_type(4))) float f4;    // MFMA accumulator

typedef unsigned short u16;
typedef unsigned int u32;

__device__ inline u16 f2b(float f) {
  __hip_bfloat16 h = __float2bfloat16(f);
  union { __hip_bfloat16 h; u16 u; } v; v.h = h; return v.u;
}
__device__ inline float b2f(u16 b) {
  union { u32 u; float f; } v; v.u = ((u32)b) << 16;
  return v.f;
}

// async global->LDS, 16B per lane; LDS dest is wave-uniform base + lane*16
__device__ __forceinline__ void gload16(const u16* g, u16* l) {
  __builtin_amdgcn_global_load_lds(
      (__attribute__((address_space(1))) void*)(g),
      (__attribute__((address_space(3))) void*)(l),
      16, 0, 0);
}

// ---------------- fused prep 1: cast x to bf16 + both weight transposes ----------------
__global__ __launch_bounds__(256) void k_prep1(const float* __restrict__ x,
                                               const float* __restrict__ Wqkv,
                                               const float* __restrict__ Wo,
                                               u16* __restrict__ xb,
                                               u16* __restrict__ wqkvT,
                                               u16* __restrict__ woT) {
  int idx = blockIdx.x;
  if (idx < 4096) {
    int i = (idx * 256 + threadIdx.x) * 4;
    float4 v = *(const float4*)&x[i];
    ushort4 o;
    o.x = f2b(v.x); o.y = f2b(v.y); o.z = f2b(v.z); o.w = f2b(v.w);
    *(ushort4*)&xb[i] = o;
    return;
  }
  __shared__ u16 t[32][33];
  const float* W; u16* WT; int K, N, bxi, byi;
  if (idx < 7168) {
    int id2 = idx - 4096;               // 96 x 32
    W = Wqkv; WT = wqkvT; K = 1024; N = 3072;
    bxi = id2 % 96; byi = id2 / 96;
  } else {
    int id2 = idx - 7168;               // 32 x 32
    W = Wo; WT = woT; K = 1024; N = 1024;
    bxi = id2 & 31; byi = id2 >> 5;
  }
  int bx = bxi * 32, by = byi * 32;
  int xx = threadIdx.x & 31, yy = threadIdx.x >> 5;
  for (int j = 0; j < 4; ++j) {
    int r = yy + j * 8;
    t[r][xx] = f2b(W[(size_t)(by + r) * N + bx + xx]);
  }
  __syncthreads();
  for (int j = 0; j < 4; ++j) {
    int r = yy + j * 8;
    WT[(size_t)(bx + r) * K + by + xx] = t[xx][r];
  }
}

// ---------------- GEMM: C[M,N] = A[M,K] * Bt[N,K], bf16 in ----------------
template <bool F32OUT>
__global__ __launch_bounds__(256) void k_gemm(const u16* __restrict__ A,
                                              const u16* __restrict__ Bt,
                                              void* __restrict__ Cout,
                                              int M, int N, int K) {
  __shared__ u16 As[2][128 * 64];
  __shared__ u16 Bs[2][128 * 64];
  const int tid = threadIdx.x;
  const int lane = tid & 63, wid = tid >> 6;
  const int l15 = lane & 15, lg = lane >> 4;
  const int bm = blockIdx.x * 128, bn = blockIdx.y * 128;
  const int wr = (wid >> 1) * 64, wc = (wid & 1) * 64;

  f4 acc[4][4] = {};

  const int srow = wid * 32 + (lane >> 3);
  const int scol = (lane & 7) * 8;
  const u16* gA = A  + (size_t)(bm + srow) * K + scol;
  const u16* gB = Bt + (size_t)(bn + srow) * K + scol;

  const int nk = K >> 6;

  {
    const u16* ga = gA; const u16* gb = gB;
    u16* la = &As[0][(wid * 32) * 64];
    u16* lb = &Bs[0][(wid * 32) * 64];
    #pragma unroll
    for (int c = 0; c < 4; ++c) {
      gload16(ga, la);
      gload16(gb, lb);
      ga += (size_t)8 * K; gb += (size_t)8 * K;
      la += 8 * 64;        lb += 8 * 64;
    }
  }
  __syncthreads();

  for (int t = 0; t < nk; ++t) {
    if (t + 1 < nk) {
      int kb = (t + 1) << 6;
      const u16* ga = gA + kb; const u16* gb = gB + kb;
      u16* la = &As[(t + 1) & 1][(wid * 32) * 64];
      u16* lb = &Bs[(t + 1) & 1][(wid * 32) * 64];
      #pragma unroll
      for (int c = 0; c < 4; ++c) {
        gload16(ga, la);
        gload16(gb, lb);
        ga += (size_t)8 * K; gb += (size_t)8 * K;
        la += 8 * 64;        lb += 8 * 64;
      }
    }
    const u16* as = &As[t & 1][0];
    const u16* bs = &Bs[t & 1][0];
    #pragma unroll
    for (int kk = 0; kk < 2; ++kk) {
      bh8 a[4], b[4];
      #pragma unroll
      for (int m = 0; m < 4; ++m)
        a[m] = *(const bh8*)&as[(wr + m * 16 + l15) * 64 + kk * 32 + lg * 8];
      #pragma unroll
      for (int n = 0; n < 4; ++n)
        b[n] = *(const bh8*)&bs[(wc + n * 16 + l15) * 64 + kk * 32 + lg * 8];
      #pragma unroll
      for (int m = 0; m < 4; ++m)
        #pragma unroll
        for (int n = 0; n < 4; ++n)
          acc[m][n] = __builtin_amdgcn_mfma_f32_16x16x32_bf16(a[m], b[n], acc[m][n], 0, 0, 0);
    }
    __syncthreads();
  }

  for (int m = 0; m < 4; ++m)
    for (int n = 0; n < 4; ++n)
      for (int r = 0; r < 4; ++r) {
        int row = bm + wr + m * 16 + lg * 4 + r;
        int col = bn + wc + n * 16 + l15;
        float v = acc[m][n][r];
        if constexpr (F32OUT) ((float*)Cout)[(size_t)row * N + col] = v;
        else                  ((u16*)Cout)[(size_t)row * N + col]  = f2b(v);
      }
}

// ---------------- fused prep 2: vectorized RMSNorm+RoPE (Q,K) + V transpose ----------------
// blocks 0..2047: norm/rope. wave = (b,l,{q|k}); lane: head=lane>>2, quarter=lane&3,
// holds d = qd*8..+7 and d+32 (RoPE partner in-lane). blocks 2048+: V transpose.
__global__ __launch_bounds__(256) void k_prep2(const u16* __restrict__ qkv,
                                               const float* __restrict__ qw,
                                               const float* __restrict__ kw,
                                               const float* __restrict__ cosp,
                                               const float* __restrict__ sinp,
                                               u16* __restrict__ Q,
                                               u16* __restrict__ K,
                                               u16* __restrict__ Vt) {
  const float CSC = 0.125f * 1.44269504088896f;
  int idx = blockIdx.x;
  if (idx < 2048) {
    int wid = threadIdx.x >> 6, lane = threadIdx.x & 63;
    int gw = idx * 4 + wid;
    int isK = gw & 1;
    int bl = gw >> 1;
    int l = bl & 2047, b = bl >> 11;
    int h = lane >> 2, qd = lane & 3;
    const u16* src = qkv + (size_t)bl * 3072 + isK * 1024 + h * 64 + qd * 8;
    bh8 t1 = *(const bh8*)src;
    bh8 t2 = *(const bh8*)(src + 32);
    float a1[8], a2[8];
    float ss = 0.0f;
    #pragma unroll
    for (int j = 0; j < 8; ++j) {
      a1[j] = b2f((u16)t1[j]); a2[j] = b2f((u16)t2[j]);
      ss += a1[j] * a1[j] + a2[j] * a2[j];
    }
    ss += __shfl_xor(ss, 1, 64);
    ss += __shfl_xor(ss, 2, 64);
    float rr = rsqrtf(ss * (1.0f / 64.0f) + 1e-6f);
    const float* wt = isK ? kw : qw;
    float w1[8], w2[8], cc[8], sn[8];
    *(float4*)&w1[0] = *(const float4*)&wt[qd * 8];
    *(float4*)&w1[4] = *(const float4*)&wt[qd * 8 + 4];
    *(float4*)&w2[0] = *(const float4*)&wt[32 + qd * 8];
    *(float4*)&w2[4] = *(const float4*)&wt[32 + qd * 8 + 4];
    *(float4*)&cc[0] = *(const float4*)&cosp[l * 32 + qd * 8];
    *(float4*)&cc[4] = *(const float4*)&cosp[l * 32 + qd * 8 + 4];
    *(float4*)&sn[0] = *(const float4*)&sinp[l * 32 + qd * 8];
    *(float4*)&sn[4] = *(const float4*)&sinp[l * 32 + qd * 8 + 4];
    float scl = isK ? 1.0f : CSC;
    bh8 o1, o2;
    #pragma unroll
    for (int j = 0; j < 8; ++j) {
      float x1 = a1[j] * rr * w1[j];
      float x2 = a2[j] * rr * w2[j];
      o1[j] = (short)f2b((x1 * cc[j] - x2 * sn[j]) * scl);
      o2[j] = (short)f2b((x1 * sn[j] + x2 * cc[j]) * scl);
    }
    u16* dst = (isK ? K : Q) + ((size_t)(b * 16 + h) * 2048 + l) * 64 + qd * 8;
    *(bh8*)dst = o1;
    *(bh8*)(dst + 32) = o2;
  } else {
    __shared__ u16 t[32][33];
    int v = idx - 2048;                 // 64 x 2 x 32
    int bxi = v & 63, byi = (v >> 6) & 1, bh = v >> 7;
    int b = bh >> 4, h = bh & 15;
    int lb = bxi * 32, db = byi * 32;
    int xx = threadIdx.x & 31, yy = threadIdx.x >> 5;
    const u16* src = qkv + (size_t)b * 2048 * 3072 + 2048 + h * 64;
    for (int j = 0; j < 4; ++j) {
      int r = yy + j * 8;
      t[r][xx] = src[(size_t)(lb + r) * 3072 + db + xx];
    }
    __syncthreads();
    u16* dst = Vt + (size_t)bh * 64 * 2048;
    for (int j = 0; j < 4; ++j) {
      int r = yy + j * 8;
      dst[(size_t)(db + r) * 2048 + lb + xx] = t[xx][r];
    }
  }
}

// ---------------- flash attention, causal; swapped-MFMA, in-register P, fine split-K ----------------
// grid (40, B*H). id 0..3: qt=id full. 4..11: 2-way qt=4+. 12..23: 3-way qt=8+.
// 24..39: 4-way qt=12+. All chunks <= 8 tiles. Longest dispatched first.
__global__ __launch_bounds__(256, 4) void k_attn(const u16* __restrict__ Q,
                                                 const u16* __restrict__ K,
                                                 const u16* __restrict__ Vt,
                                                 u16* __restrict__ O,
                                                 u16* __restrict__ Opart,
                                                 float2* __restrict__ Ml) {
  __shared__ u16 Ks[2][64 * 64];   // [k-local][d], XOR-swizzled chunks
  __shared__ u16 Vs[2][64 * 64];   // [d][k-local], XOR-swizzled chunks

  const int bh = blockIdx.y;
  const int b = bh >> 4, h = bh & 15;
  const int wid = threadIdx.x >> 6, lane = threadIdx.x & 63;
  const int l15 = lane & 15, lg = lane >> 4;

  const int id = 39 - (int)blockIdx.x;    // longest work dispatched first
  int qt, t0, t1, slot;
  if (id < 4) { qt = id; t0 = 0; t1 = 2 * qt + 2; slot = -1; }
  else if (id < 12) {
    int p = id - 4; qt = 4 + (p >> 1); int half = p & 1;
    int nt = qt + 1; t0 = half * nt; t1 = t0 + nt;
    slot = bh * 36 + (qt - 4) * 2 + half;
  } else if (id < 24) {
    int p = id - 12; qt = 8 + p / 3; int part = p % 3;
    int T = 2 * qt + 2; t0 = part * T / 3; t1 = (part + 1) * T / 3;
    slot = bh * 36 + 8 + (qt - 8) * 3 + part;
  } else {
    int p = id - 24; qt = 12 + (p >> 2); int part = p & 3;
    int T = 2 * qt + 2; t0 = part * T / 4; t1 = (part + 1) * T / 4;
    slot = bh * 36 + 20 + (qt - 12) * 4 + part;
  }
  const int qb = qt * 128 + wid * 32;

  const u16* Qp = Q  + (size_t)bh * 2048 * 64;
  const u16* Kp = K  + (size_t)bh * 2048 * 64;
  const u16* Vp = Vt + (size_t)bh * 64 * 2048;

  const int sr0 = wid * 8 + (lane >> 3);
  const int sc  = lane & 7;

  bh8 aq[2][2];
  #pragma unroll
  for (int qi = 0; qi < 2; ++qi)
    #pragma unroll
    for (int hh = 0; hh < 2; ++hh)
      aq[qi][hh] = *(const bh8*)&Qp[(size_t)(qb + qi * 16 + l15) * 64 + hh * 32 + lg * 8];

  bh8 ones;
  #pragma unroll
  for (int j = 0; j < 8; ++j) ones[j] = (short)0x3F80;

  f4 acc[2][4] = {};
  float mrow[2] = {-1e30f, -1e30f};   // log2 domain
  float lrow[2] = {0.0f, 0.0f};

  const int tmax = (qb + 31) >> 6;

  {
    int kb0 = t0 * 64;
    int r0 = sr0, r1 = 32 + sr0;
    gload16(Kp + (size_t)(kb0 + r0) * 64 + (size_t)((sc ^ (r0 & 7)) * 8), &Ks[t0 & 1][(wid * 8) * 64]);
    gload16(Kp + (size_t)(kb0 + r1) * 64 + (size_t)((sc ^ (r1 & 7)) * 8), &Ks[t0 & 1][(32 + wid * 8) * 64]);
    gload16(Vp + (size_t)r0 * 2048 + kb0 + (size_t)((sc ^ (r0 & 7)) * 8), &Vs[t0 & 1][(wid * 8) * 64]);
    gload16(Vp + (size_t)r1 * 2048 + kb0 + (size_t)((sc ^ (r1 & 7)) * 8), &Vs[t0 & 1][(32 + wid * 8) * 64]);
  }
  __syncthreads();

  for (int t = t0; t < t1; ++t) {
    if (t + 1 < t1) {
      int kb = (t + 1) * 64;
      int nb = (t + 1) & 1;
      int r0 = sr0, r1 = 32 + sr0;
      gload16(Kp + (size_t)(kb + r0) * 64 + (size_t)((sc ^ (r0 & 7)) * 8), &Ks[nb][(wid * 8) * 64]);
      gload16(Kp + (size_t)(kb + r1) * 64 + (size_t)((sc ^ (r1 & 7)) * 8), &Ks[nb][(32 + wid * 8) * 64]);
      gload16(Vp + (size_t)r0 * 2048 + kb + (size_t)((sc ^ (r0 & 7)) * 8), &Vs[nb][(wid * 8) * 64]);
      gload16(Vp + (size_t)r1 * 2048 + kb + (size_t)((sc ^ (r1 & 7)) * 8), &Vs[nb][(32 + wid * 8) * 64]);
    }
    if (t <= tmax) {
      const int kb = t * 64;
      const bool masked = (t == tmax);
      const u16* ks = &Ks[t & 1][0];
      const u16* vs = &Vs[t & 1][0];

      // ---- QK^T (swapped): D col=q; Q pre-scaled (log2 domain) ----
      f4 sc4[4][2] = {};
      __builtin_amdgcn_s_setprio(1);
      #pragma unroll
      for (int kq = 0; kq < 4; ++kq) {
        int row = kq * 16 + l15;
        int cs = row & 7;
        bh8 ka0 = *(const bh8*)&ks[row * 64 + ((0 + lg) ^ cs) * 8];
        bh8 ka1 = *(const bh8*)&ks[row * 64 + ((4 + lg) ^ cs) * 8];
        #pragma unroll
        for (int qi = 0; qi < 2; ++qi) {
          sc4[kq][qi] = __builtin_amdgcn_mfma_f32_16x16x32_bf16(ka0, aq[qi][0], sc4[kq][qi], 0, 0, 0);
          sc4[kq][qi] = __builtin_amdgcn_mfma_f32_16x16x32_bf16(ka1, aq[qi][1], sc4[kq][qi], 0, 0, 0);
        }
      }
      __builtin_amdgcn_s_setprio(0);

      // ---- online softmax (log2 domain), defer-max THR=8, mask only diag ----
      #pragma unroll
      for (int qi = 0; qi < 2; ++qi) {
        if (masked) {
          int q = qb + qi * 16 + l15;
          #pragma unroll
          for (int kq = 0; kq < 4; ++kq)
            #pragma unroll
            for (int r = 0; r < 4; ++r)
              if (kb + kq * 16 + lg * 4 + r > q) sc4[kq][qi][r] = -1e30f;
        }
        float mx = -1e30f;
        #pragma unroll
        for (int kq = 0; kq < 4; ++kq)
          #pragma unroll
          for (int r = 0; r < 4; ++r)
            mx = fmaxf(mx, sc4[kq][qi][r]);
        mx = fmaxf(mx, __shfl_xor(mx, 16, 64));
        mx = fmaxf(mx, __shfl_xor(mx, 32, 64));
        if (__any(mx > mrow[qi] + 8.0f)) {
          float mnew = fmaxf(mrow[qi], mx);
          float fac = exp2f(mrow[qi] - mnew);
          mrow[qi] = mnew;
          lrow[qi] *= fac;
          #pragma unroll
          for (int n = 0; n < 4; ++n)
            #pragma unroll
            for (int r = 0; r < 4; ++r) acc[qi][n][r] *= fac;
        }
        #pragma unroll
        for (int kq = 0; kq < 4; ++kq)
          #pragma unroll
          for (int r = 0; r < 4; ++r)
            sc4[kq][qi][r] = exp2f(sc4[kq][qi][r] - mrow[qi]);
      }

      // ---- P redistribute IN-REGISTER (2 butterfly rounds within lg-quad) ----
      // source: P[k=kq*16+lg*4+r][q=l15]; target: pb[g][qi] word c = P-pair
      // w = g*16+lg*4+c. Routing: dest bit1 = kq&1, dest bit0 = src_lg>>1.
      bh8 pb[2][2];
      #pragma unroll
      for (int qi = 0; qi < 2; ++qi) {
        u32 W[8];
        #pragma unroll
        for (int kq = 0; kq < 4; ++kq) {
          W[kq * 2 + 0] = (u32)f2b(sc4[kq][qi][0]) | ((u32)f2b(sc4[kq][qi][1]) << 16);
          W[kq * 2 + 1] = (u32)f2b(sc4[kq][qi][2]) | ((u32)f2b(sc4[kq][qi][3]) << 16);
        }
        const bool b1 = (lg & 2) != 0, b0 = (lg & 1) != 0;
        u32 r0 = __shfl_xor(b1 ? W[0] : W[2], 32, 64);
        u32 r1 = __shfl_xor(b1 ? W[1] : W[3], 32, 64);
        u32 r2 = __shfl_xor(b1 ? W[4] : W[6], 32, 64);
        u32 r3 = __shfl_xor(b1 ? W[5] : W[7], 32, 64);
        u32 k0 = b1 ? W[2] : W[0];
        u32 k1 = b1 ? W[3] : W[1];
        u32 k2 = b1 ? W[6] : W[4];
        u32 k3 = b1 ? W[7] : W[5];
        const bool sr = (b1 == b0);
        u32 s0 = __shfl_xor(sr ? r0 : k0, 16, 64);
        u32 s1 = __shfl_xor(sr ? r1 : k1, 16, 64);
        u32 s2 = __shfl_xor(sr ? r2 : k2, 16, 64);
        u32 s3 = __shfl_xor(sr ? r3 : k3, 16, 64);
        union { u32 u[4]; bh8 v; } g0, g1;
        g0.u[0] = b0 ? s0 : (b1 ? r0 : k0);
        g0.u[1] = b0 ? s1 : (b1 ? r1 : k1);
        g0.u[2] = b0 ? (b1 ? k0 : r0) : s0;
        g0.u[3] = b0 ? (b1 ? k1 : r1) : s1;
        g1.u[0] = b0 ? s2 : (b1 ? r2 : k2);
        g1.u[1] = b0 ? s3 : (b1 ? r3 : k3);
        g1.u[2] = b0 ? (b1 ? k2 : r2) : s2;
        g1.u[3] = b0 ? (b1 ? k3 : r3) : s3;
        pb[0][qi] = g0.v;
        pb[1][qi] = g1.v;
      }

      // ---- PV (double-swapped) + row-sum via ones-MFMA ----
      f4 sum0 = {}, sum1 = {};
      __builtin_amdgcn_s_setprio(1);
      #pragma unroll
      for (int g = 0; g < 2; ++g) {
        #pragma unroll
        for (int n = 0; n < 4; ++n) {
          int row = n * 16 + l15;
          bh8 va = *(const bh8*)&vs[row * 64 + (((g * 4 + lg) ^ (row & 7)) * 8)];
          acc[0][n] = __builtin_amdgcn_mfma_f32_16x16x32_bf16(va, pb[g][0], acc[0][n], 0, 0, 0);
          acc[1][n] = __builtin_amdgcn_mfma_f32_16x16x32_bf16(va, pb[g][1], acc[1][n], 0, 0, 0);
        }
        sum0 = __builtin_amdgcn_mfma_f32_16x16x32_bf16(ones, pb[g][0], sum0, 0, 0, 0);
        sum1 = __builtin_amdgcn_mfma_f32_16x16x32_bf16(ones, pb[g][1], sum1, 0, 0, 0);
      }
      __builtin_amdgcn_s_setprio(0);
      lrow[0] += sum0[0];
      lrow[1] += sum1[0];
    }
    __syncthreads();
  }

  if (slot < 0) {
    #pragma unroll
    for (int qi = 0; qi < 2; ++qi) {
      float inv = 1.0f / lrow[qi];
      int q = qb + qi * 16 + l15;
      #pragma unroll
      for (int n = 0; n < 4; ++n) {
        ushort4 w4;
        w4.x = f2b(acc[qi][n][0] * inv);
        w4.y = f2b(acc[qi][n][1] * inv);
        w4.z = f2b(acc[qi][n][2] * inv);
        w4.w = f2b(acc[qi][n][3] * inv);
        *(ushort4*)&O[((size_t)b * 2048 + q) * 1024 + h * 64 + n * 16 + lg * 4] = w4;
      }
    }
  } else {
    u16* op = Opart + (size_t)slot * 8192;
    #pragma unroll
    for (int qi = 0; qi < 2; ++qi) {
      int rloc = wid * 32 + qi * 16 + l15;
      #pragma unroll
      for (int n = 0; n < 4; ++n) {
        ushort4 w4;
        w4.x = f2b(acc[qi][n][0]); w4.y = f2b(acc[qi][n][1]);
        w4.z = f2b(acc[qi][n][2]); w4.w = f2b(acc[qi][n][3]);
        *(ushort4*)&op[(size_t)rloc * 64 + n * 16 + lg * 4] = w4;
      }
      if (lg == 0) Ml[slot * 128 + rloc] = make_float2(mrow[qi], lrow[qi]);
    }
  }
}

// ---------------- combine split-K partials (2/3/4-way) ----------------
__global__ __launch_bounds__(256) void k_comb(const u16* __restrict__ Opart,
                                              const float2* __restrict__ Ml,
                                              u16* __restrict__ O) {
  int qt = 4 + (int)blockIdx.x;     // 4..15
  int bh = blockIdx.y;
  int b = bh >> 4, h = bh & 15;
  int ways = qt < 8 ? 2 : (qt < 12 ? 3 : 4);
  int base = bh * 36 + (qt < 8 ? (qt - 4) * 2 : qt < 12 ? 8 + (qt - 8) * 3 : 20 + (qt - 12) * 4);
  int row = threadIdx.x >> 1;
  int db  = (threadIdx.x & 1) * 32;

  float2 ml[4]; float wgt[4];
  float M = -1e30f;
  #pragma unroll
  for (int w = 0; w < 4; ++w)
    if (w < ways) { ml[w] = Ml[(base + w) * 128 + row]; M = fmaxf(M, ml[w].x); }
  float l = 0.0f;
  #pragma unroll
  for (int w = 0; w < 4; ++w)
    if (w < ways) { wgt[w] = exp2f(ml[w].x - M); l += wgt[w] * ml[w].y; }
  float inv = 1.0f / l;

  u16* dst = O + ((size_t)b * 2048 + qt * 128 + row) * 1024 + h * 64 + db;
  #pragma unroll
  for (int j = 0; j < 32; j += 8) {
    float a[8] = {};
    #pragma unroll
    for (int w = 0; w < 4; ++w)
      if (w < ways) {
        bh8 v = *(const bh8*)&Opart[(size_t)(base + w) * 8192 + (size_t)row * 64 + db + j];
        #pragma unroll
        for (int e = 0; e < 8; ++e) a[e] += wgt[w] * b2f((u16)v[e]);
      }
    bh8 o;
    #pragma unroll
    for (int e = 0; e < 8; ++e) o[e] = (short)f2b(a[e] * inv);
    *(bh8*)&dst[j] = o;
  }
}

extern "C" void kernel_launch(void* const* d_in, const int* in_sizes, int n_in,
                              void* d_out, int out_size, void* d_ws, size_t ws_size,
                              hipStream_t stream) {
  (void)in_sizes; (void)n_in; (void)out_size; (void)ws_size;
  const float* x    = (const float*)d_in[0];
  const float* Wqkv = (const float*)d_in[1];
  const float* Wo   = (const float*)d_in[2];
  const float* qw   = (const float*)d_in[3];
  const float* kw   = (const float*)d_in[4];
  const float* cosp = (const float*)d_in[5];
  const float* sinp = (const float*)d_in[6];
  float* out = (float*)d_out;

  char* ws = (char*)d_ws;
  u16* xb    = (u16*)(ws);                 //  8,388,608 B  x bf16 [4096][1024]
  u16* wqkvT = (u16*)(ws + 8388608);       //  6,291,456 B  Wqkv^T bf16
  u16* woT   = (u16*)(ws + 14680064);      //  2,097,152 B  Wo^T bf16
  u16* qkv   = (u16*)(ws + 16777216);      // 25,165,824 B  qkv bf16 [4096][3072]
  u16* Qb    = (u16*)(ws + 41943040);      //  8,388,608 B  [B,H,L,D]
  u16* Kb    = (u16*)(ws + 50331648);      //  8,388,608 B
  u16* Vtb   = (u16*)(ws + 58720256);      //  8,388,608 B  [B,H,D,L]
  u16* AO    = (u16*)(ws + 67108864);      //  8,388,608 B  attn_out bf16
  // split-K partials overlay the dead qkv region (1152 slots)
  u16*    Opart = (u16*)(ws + 16777216);     // 1152 * 8192 * 2B = 18,874,368 B
  float2* Mlb   = (float2*)(ws + 35651584);  // 1152 * 128 * 8B  =  1,179,648 B

  k_prep1<<<8192, 256, 0, stream>>>(x, Wqkv, Wo, xb, wqkvT, woT);
  k_gemm<false><<<dim3(32, 24), 256, 0, stream>>>(xb, wqkvT, qkv, 4096, 3072, 1024);
  k_prep2<<<6144, 256, 0, stream>>>(qkv, qw, kw, cosp, sinp, Qb, Kb, Vtb);
  k_attn<<<dim3(40, 32), 256, 0, stream>>>(Qb, Kb, Vtb, AO, Opart, Mlb);
  k_comb<<<dim3(12, 32), 256, 0, stream>>>(Opart, Mlb, AO);
  k_gemm<true><<<dim3(32, 8), 256, 0, stream>>>(AO, woT, out, 4096, 1024, 1024);
}